// Round 1
// baseline (1888.644 us; speedup 1.0000x reference)
//
#include <hip/hip_runtime.h>

#define N_NODES 50000
#define N_EDGES 800000
#define IN_DIM  256
#define NH      4
#define HD      128   // NH * 32
#define NEG_SLOPE 0.2f

// ---------------------------------------------------------------------------
// K1: fused GEMM (ft = feat @ W) + per-node head scalars + reparameterize.
// Block = 128 threads (thread c owns output column c), 16 rows per block.
// feat row values are block-uniform -> compiler emits scalar loads; W reads
// are lane-coalesced (c contiguous) and L2-resident (W = 128 KB).
// ---------------------------------------------------------------------------
__global__ __launch_bounds__(128) void k1_gemm_scalars(
    const float* __restrict__ feat, const float* __restrict__ W,
    const float* __restrict__ mu_src, const float* __restrict__ mu_dst,
    const float* __restrict__ lam_src,
    const float* __restrict__ eps_src, const float* __restrict__ eps_dst,
    float* __restrict__ ft_ws, float* __restrict__ z_src_ws,
    float* __restrict__ z_dst_ws,
    float* __restrict__ mu_out, float* __restrict__ lam_out)
{
    const int c  = threadIdx.x;          // column 0..127
    const int r0 = blockIdx.x * 16;      // 50000 = 3125 * 16, exact

    float acc[16];
#pragma unroll
    for (int r = 0; r < 16; ++r) acc[r] = 0.0f;

    const float* fbase = feat + (size_t)r0 * IN_DIM;
    for (int k = 0; k < IN_DIM; ++k) {
        const float w = W[k * HD + c];
#pragma unroll
        for (int r = 0; r < 16; ++r)
            acc[r] = fmaf(fbase[r * IN_DIM + k], w, acc[r]);
    }

    // store ft (coalesced)
    float* ftb = ft_ws + (size_t)r0 * HD;
#pragma unroll
    for (int r = 0; r < 16; ++r) ftb[r * HD + c] = acc[r];

    // per-head reductions: dot(ft_row_h, mu_src_h / mu_dst_h / lam_src_h)
    const float ms = mu_src[c];
    const float md = mu_dst[c];
    const float ls = lam_src[c];
    const int h      = c >> 5;
    const int lane_d = c & 31;

#pragma unroll
    for (int r = 0; r < 16; ++r) {
        float pm = acc[r] * ms;
        float pd = acc[r] * md;
        float pl = acc[r] * ls;
#pragma unroll
        for (int m = 16; m >= 1; m >>= 1) {
            pm += __shfl_xor(pm, m, 64);
            pd += __shfl_xor(pd, m, 64);
            pl += __shfl_xor(pl, m, 64);
        }
        if (lane_d == 0) {
            const int row = r0 + r;
            const float mu_s  = pm;
            const float mu_d  = pd;
            const float lam_s = pl;          // lam_d == lam_s in reference
            const float sdev  = expf(0.5f * lam_s);
            z_src_ws[row * NH + h] = eps_src[row * NH + h] * sdev + mu_s;
            z_dst_ws[row * NH + h] = eps_dst[row * NH + h] * sdev + mu_d;
            mu_out[row * NH + h]  = mu_s + mu_d;
            lam_out[row * NH + h] = 2.0f * lam_s;
        }
    }
}

// ---------------------------------------------------------------------------
// K2: per-edge un-normalized softmax weight (no max-subtraction needed:
// |e2| <= ~15 so exp() is fp32-safe; ratio to denom is identical).
// ---------------------------------------------------------------------------
__global__ __launch_bounds__(256) void k2_edge_exp(
    const int* __restrict__ src, const int* __restrict__ dst,
    const float* __restrict__ ppmi,
    const float4* __restrict__ z_src_ws, const float4* __restrict__ z_dst_ws,
    float4* __restrict__ w_ws, float* __restrict__ denom)
{
    const int e = blockIdx.x * 256 + threadIdx.x;
    if (e >= N_EDGES) return;
    const int s  = src[e];
    const int d0 = dst[e];

    // scale = clip(log(clip(log(ppmi),1,inf)),1,inf)  (== 1.0 for this data)
    const float lp    = fmaxf(__logf(ppmi[e]), 1.0f);
    const float scale = fmaxf(__logf(lp), 1.0f);

    const float4 zs = z_src_ws[s];
    const float4 zd = z_dst_ws[d0];
    float z[4] = {zs.x + zd.x, zs.y + zd.y, zs.z + zd.z, zs.w + zd.w};
    float w[4];
#pragma unroll
    for (int h = 0; h < 4; ++h) {
        float v = z[h];
        v = (v >= 0.0f) ? v : NEG_SLOPE * v;   // leaky_relu
        w[h] = __expf(v * scale);
        atomicAdd(&denom[d0 * NH + h], w[h]);
    }
    w_ws[e] = make_float4(w[0], w[1], w[2], w[3]);
}

// ---------------------------------------------------------------------------
// K3: weighted scatter-sum aggregation. 32 threads per edge, float4 per
// thread: gather ft[src] (dwordx4, coalesced 512B/edge) and atomicAdd into
// rst[dst].
// ---------------------------------------------------------------------------
__global__ __launch_bounds__(256) void k3_aggregate(
    const int* __restrict__ src, const int* __restrict__ dst,
    const float4* __restrict__ ft4, const float* __restrict__ w_ws,
    const float* __restrict__ denom, float* __restrict__ rst)
{
    const int e  = blockIdx.x * 8 + (threadIdx.x >> 5);  // 8 edges / block
    const int c4 = threadIdx.x & 31;                     // float4 index 0..31
    if (e >= N_EDGES) return;

    const int s  = src[e];
    const int d0 = dst[e];
    const int h  = c4 >> 3;                              // head = (c4*4)/32

    const float a = w_ws[e * NH + h] / denom[d0 * NH + h];
    const float4 f = ft4[(size_t)s * 32 + c4];

    float* out = rst + (size_t)d0 * HD + c4 * 4;
    atomicAdd(out + 0, f.x * a);
    atomicAdd(out + 1, f.y * a);
    atomicAdd(out + 2, f.z * a);
    atomicAdd(out + 3, f.w * a);
}

// ---------------------------------------------------------------------------
extern "C" void kernel_launch(void* const* d_in, const int* in_sizes, int n_in,
                              void* d_out, int out_size, void* d_ws, size_t ws_size,
                              hipStream_t stream)
{
    const float* feat    = (const float*)d_in[0];
    const int*   src     = (const int*)  d_in[1];
    const int*   dst     = (const int*)  d_in[2];
    const float* ppmi    = (const float*)d_in[3];
    const float* eps_src = (const float*)d_in[4];
    const float* eps_dst = (const float*)d_in[5];
    const float* W       = (const float*)d_in[6];
    const float* mu_src  = (const float*)d_in[7];
    const float* mu_dst  = (const float*)d_in[8];
    const float* lam_src = (const float*)d_in[9];
    // d_in[10] = lam_dst: unused by the reference math

    float* out     = (float*)d_out;
    float* rst     = out;                                 // N*HD
    float* mu_out  = out + (size_t)N_NODES * HD;          // N*NH
    float* lam_out = mu_out + (size_t)N_NODES * NH;       // N*NH

    float* ws     = (float*)d_ws;
    float* ft_ws  = ws;                                   // N*HD   (25.6 MB)
    float* zs_ws  = ft_ws + (size_t)N_NODES * HD;         // N*NH
    float* zd_ws  = zs_ws + (size_t)N_NODES * NH;         // N*NH
    float* den_ws = zd_ws + (size_t)N_NODES * NH;         // N*NH
    float* w_ws   = den_ws + (size_t)N_NODES * NH;        // E*NH   (12.8 MB)

    // rst is accumulated with atomics; denom likewise -> zero them.
    hipMemsetAsync(rst,    0, (size_t)N_NODES * HD * sizeof(float), stream);
    hipMemsetAsync(den_ws, 0, (size_t)N_NODES * NH * sizeof(float), stream);

    k1_gemm_scalars<<<N_NODES / 16, 128, 0, stream>>>(
        feat, W, mu_src, mu_dst, lam_src, eps_src, eps_dst,
        ft_ws, zs_ws, zd_ws, mu_out, lam_out);

    k2_edge_exp<<<(N_EDGES + 255) / 256, 256, 0, stream>>>(
        src, dst, ppmi, (const float4*)zs_ws, (const float4*)zd_ws,
        (float4*)w_ws, den_ws);

    k3_aggregate<<<N_EDGES / 8, 256, 0, stream>>>(
        src, dst, (const float4*)ft_ws, w_ws, den_ws, rst);
}

// Round 2
// 678.997 us; speedup vs baseline: 2.7815x; 2.7815x over previous
//
#include <hip/hip_runtime.h>

#define N_NODES 50000
#define N_EDGES 800000
#define IN_DIM  256
#define NH      4
#define HD      128   // NH * 32
#define NEG_SLOPE 0.2f
#define SCAN_BLOCKS ((N_NODES + 255) / 256)   // 196

// ---------------------------------------------------------------------------
// K1: fused GEMM (ft = feat @ W) + per-node head scalars + reparameterize.
// ---------------------------------------------------------------------------
__global__ __launch_bounds__(128) void k1_gemm_scalars(
    const float* __restrict__ feat, const float* __restrict__ W,
    const float* __restrict__ mu_src, const float* __restrict__ mu_dst,
    const float* __restrict__ lam_src,
    const float* __restrict__ eps_src, const float* __restrict__ eps_dst,
    float* __restrict__ ft_ws, float* __restrict__ z_src_ws,
    float* __restrict__ z_dst_ws,
    float* __restrict__ mu_out, float* __restrict__ lam_out)
{
    const int c  = threadIdx.x;          // column 0..127
    const int r0 = blockIdx.x * 16;      // 50000 = 3125 * 16, exact

    float acc[16];
#pragma unroll
    for (int r = 0; r < 16; ++r) acc[r] = 0.0f;

    const float* fbase = feat + (size_t)r0 * IN_DIM;
    for (int k = 0; k < IN_DIM; ++k) {
        const float w = W[k * HD + c];
#pragma unroll
        for (int r = 0; r < 16; ++r)
            acc[r] = fmaf(fbase[r * IN_DIM + k], w, acc[r]);
    }

    float* ftb = ft_ws + (size_t)r0 * HD;
#pragma unroll
    for (int r = 0; r < 16; ++r) ftb[r * HD + c] = acc[r];

    const float ms = mu_src[c];
    const float md = mu_dst[c];
    const float ls = lam_src[c];
    const int h      = c >> 5;
    const int lane_d = c & 31;

#pragma unroll
    for (int r = 0; r < 16; ++r) {
        float pm = acc[r] * ms;
        float pd = acc[r] * md;
        float pl = acc[r] * ls;
#pragma unroll
        for (int m = 16; m >= 1; m >>= 1) {
            pm += __shfl_xor(pm, m, 64);
            pd += __shfl_xor(pd, m, 64);
            pl += __shfl_xor(pl, m, 64);
        }
        if (lane_d == 0) {
            const int row = r0 + r;
            const float mu_s  = pm;
            const float mu_d  = pd;
            const float lam_s = pl;          // lam_d == lam_s in reference
            const float sdev  = expf(0.5f * lam_s);
            z_src_ws[row * NH + h] = eps_src[row * NH + h] * sdev + mu_s;
            z_dst_ws[row * NH + h] = eps_dst[row * NH + h] * sdev + mu_d;
            mu_out[row * NH + h]  = mu_s + mu_d;
            lam_out[row * NH + h] = 2.0f * lam_s;
        }
    }
}

__device__ __forceinline__ void edge_w(float4 zs, float4 zd, float scale,
                                       float w[4])
{
    float z[4] = {zs.x + zd.x, zs.y + zd.y, zs.z + zd.z, zs.w + zd.w};
#pragma unroll
    for (int h = 0; h < 4; ++h) {
        float v = z[h];
        v = (v >= 0.0f) ? v : NEG_SLOPE * v;   // leaky_relu
        w[h] = __expf(v * scale);
    }
}

__device__ __forceinline__ float edge_scale(float p)
{
    // clip(log(clip(log(ppmi),1,inf)),1,inf)
    const float lp = fmaxf(__logf(p), 1.0f);
    return fmaxf(__logf(lp), 1.0f);
}

// ---------------------------------------------------------------------------
// K2: per-edge un-normalized softmax weight -> denom, plus dst histogram.
// (no max-subtraction: |e2| small, exp() fp32-safe, ratio identical)
// ---------------------------------------------------------------------------
__global__ __launch_bounds__(256) void k2_edge_exp(
    const int* __restrict__ src, const int* __restrict__ dst,
    const float* __restrict__ ppmi,
    const float4* __restrict__ z_src_ws, const float4* __restrict__ z_dst_ws,
    float* __restrict__ denom, int* __restrict__ counts)
{
    const int e = blockIdx.x * 256 + threadIdx.x;
    if (e >= N_EDGES) return;
    const int s  = src[e];
    const int d0 = dst[e];

    float w[4];
    edge_w(z_src_ws[s], z_dst_ws[d0], edge_scale(ppmi[e]), w);
#pragma unroll
    for (int h = 0; h < 4; ++h) atomicAdd(&denom[d0 * NH + h], w[h]);
    atomicAdd(&counts[d0], 1);
}

// ---------------------------------------------------------------------------
// Scan: counts[N] -> exclusive offsets (3 small kernels)
// ---------------------------------------------------------------------------
__global__ __launch_bounds__(256) void k_scan_local(
    const int* __restrict__ counts, int* __restrict__ local,
    int* __restrict__ bsums)
{
    __shared__ int sh[256];
    const int t = threadIdx.x;
    const int i = blockIdx.x * 256 + t;
    const int v = (i < N_NODES) ? counts[i] : 0;
    sh[t] = v;
    __syncthreads();
#pragma unroll
    for (int off = 1; off < 256; off <<= 1) {
        int x = (t >= off) ? sh[t - off] : 0;
        __syncthreads();
        sh[t] += x;
        __syncthreads();
    }
    if (i < N_NODES) local[i] = sh[t] - v;     // exclusive within block
    if (t == 255) bsums[blockIdx.x] = sh[255];
}

__global__ __launch_bounds__(256) void k_scan_bsums(
    const int* __restrict__ bsums, int* __restrict__ bscan)
{
    __shared__ int sh[256];
    const int t = threadIdx.x;
    const int v = (t < SCAN_BLOCKS) ? bsums[t] : 0;
    sh[t] = v;
    __syncthreads();
#pragma unroll
    for (int off = 1; off < 256; off <<= 1) {
        int x = (t >= off) ? sh[t - off] : 0;
        __syncthreads();
        sh[t] += x;
        __syncthreads();
    }
    if (t < SCAN_BLOCKS) bscan[t] = sh[t] - v;
}

__global__ __launch_bounds__(256) void k_scan_add(
    const int* __restrict__ local, const int* __restrict__ bscan,
    int* __restrict__ offsets, int* __restrict__ cursor)
{
    const int i = blockIdx.x * 256 + threadIdx.x;
    if (i >= N_NODES) return;
    const int o = local[i] + bscan[blockIdx.x];
    offsets[i] = o;
    cursor[i]  = o;
}

// ---------------------------------------------------------------------------
// Scatter edges into dst-sorted order; recompute w and normalize by denom.
// ---------------------------------------------------------------------------
__global__ __launch_bounds__(256) void k_scatter(
    const int* __restrict__ src, const int* __restrict__ dst,
    const float* __restrict__ ppmi,
    const float4* __restrict__ z_src_ws, const float4* __restrict__ z_dst_ws,
    const float4* __restrict__ denom4, int* __restrict__ cursor,
    int* __restrict__ esrc_sorted, float4* __restrict__ a_sorted)
{
    const int e = blockIdx.x * 256 + threadIdx.x;
    if (e >= N_EDGES) return;
    const int s  = src[e];
    const int d0 = dst[e];
    const int j  = atomicAdd(&cursor[d0], 1);

    float w[4];
    edge_w(z_src_ws[s], z_dst_ws[d0], edge_scale(ppmi[e]), w);
    const float4 dn = denom4[d0];
    esrc_sorted[j] = s;
    a_sorted[j] = make_float4(w[0] / dn.x, w[1] / dn.y, w[2] / dn.z, w[3] / dn.w);
}

// ---------------------------------------------------------------------------
// K3: CSR segmented reduction. One wave per dst node, lane owns float2 of the
// 128-wide row. Register accumulate, single coalesced write. No atomics.
// ---------------------------------------------------------------------------
__global__ __launch_bounds__(64) void k3_csr(
    const int* __restrict__ offsets, const int* __restrict__ counts,
    const int* __restrict__ esrc_sorted, const float* __restrict__ a_sorted,
    const float2* __restrict__ ft2, float2* __restrict__ rst2)
{
    const int node = blockIdx.x;
    const int lane = threadIdx.x;
    const int h    = lane >> 4;                 // head = (lane*2)/32
    const int start = offsets[node];
    const int deg   = counts[node];

    float2 acc = make_float2(0.0f, 0.0f);

    int s_nx = 0; float a_nx = 0.0f;
    if (deg > 0) {
        s_nx = esrc_sorted[start];
        a_nx = a_sorted[(size_t)start * 4 + h];
    }
    for (int i = 0; i < deg; ++i) {
        const int   s_cur = s_nx;
        const float a_cur = a_nx;
        if (i + 1 < deg) {                      // prefetch next edge scalars
            s_nx = esrc_sorted[start + i + 1];
            a_nx = a_sorted[(size_t)(start + i + 1) * 4 + h];
        }
        const float2 f = ft2[(size_t)s_cur * 64 + lane];
        acc.x = fmaf(f.x, a_cur, acc.x);
        acc.y = fmaf(f.y, a_cur, acc.y);
    }
    rst2[(size_t)node * 64 + lane] = acc;
}

// ---------------------------------------------------------------------------
extern "C" void kernel_launch(void* const* d_in, const int* in_sizes, int n_in,
                              void* d_out, int out_size, void* d_ws, size_t ws_size,
                              hipStream_t stream)
{
    const float* feat    = (const float*)d_in[0];
    const int*   src     = (const int*)  d_in[1];
    const int*   dst     = (const int*)  d_in[2];
    const float* ppmi    = (const float*)d_in[3];
    const float* eps_src = (const float*)d_in[4];
    const float* eps_dst = (const float*)d_in[5];
    const float* W       = (const float*)d_in[6];
    const float* mu_src  = (const float*)d_in[7];
    const float* mu_dst  = (const float*)d_in[8];
    const float* lam_src = (const float*)d_in[9];
    // d_in[10] = lam_dst: unused by the reference math

    float* out     = (float*)d_out;
    float* rst     = out;                                 // N*HD
    float* mu_out  = out + (size_t)N_NODES * HD;          // N*NH
    float* lam_out = mu_out + (size_t)N_NODES * NH;       // N*NH

    // workspace layout (floats/ints, 4B units)
    float* ws      = (float*)d_ws;
    float* ft_ws   = ws;                                   // N*HD (25.6 MB)
    float* zs_ws   = ft_ws + (size_t)N_NODES * HD;         // N*NH
    float* zd_ws   = zs_ws + (size_t)N_NODES * NH;         // N*NH
    float* den_ws  = zd_ws + (size_t)N_NODES * NH;         // N*NH
    int*   counts  = (int*)(den_ws + (size_t)N_NODES * NH);// N     } zeroed
    int*   local   = counts + N_NODES;                     // N
    int*   offsets = local + N_NODES;                      // N
    int*   cursor  = offsets + N_NODES;                    // N
    int*   bsums   = cursor + N_NODES;                     // 256
    int*   bscan   = bsums + 256;                          // 256
    int*   esrc_s  = bscan + 256;                          // E (3.2 MB)
    float* a_sort  = (float*)(esrc_s + N_EDGES);           // E*NH (12.8 MB)

    // zero denom + counts in one shot (adjacent)
    hipMemsetAsync(den_ws, 0,
                   ((size_t)N_NODES * NH) * sizeof(float) + N_NODES * sizeof(int),
                   stream);

    k1_gemm_scalars<<<N_NODES / 16, 128, 0, stream>>>(
        feat, W, mu_src, mu_dst, lam_src, eps_src, eps_dst,
        ft_ws, zs_ws, zd_ws, mu_out, lam_out);

    k2_edge_exp<<<(N_EDGES + 255) / 256, 256, 0, stream>>>(
        src, dst, ppmi, (const float4*)zs_ws, (const float4*)zd_ws,
        den_ws, counts);

    k_scan_local<<<SCAN_BLOCKS, 256, 0, stream>>>(counts, local, bsums);
    k_scan_bsums<<<1, 256, 0, stream>>>(bsums, bscan);
    k_scan_add<<<SCAN_BLOCKS, 256, 0, stream>>>(local, bscan, offsets, cursor);

    k_scatter<<<(N_EDGES + 255) / 256, 256, 0, stream>>>(
        src, dst, ppmi, (const float4*)zs_ws, (const float4*)zd_ws,
        (const float4*)den_ws, cursor, esrc_s, (float4*)a_sort);

    k3_csr<<<N_NODES, 64, 0, stream>>>(
        offsets, counts, esrc_s, a_sort, (const float2*)ft_ws, (float2*)rst);
}

// Round 3
// 335.250 us; speedup vs baseline: 5.6335x; 2.0253x over previous
//
#include <hip/hip_runtime.h>

#define N_NODES 50000
#define N_EDGES 800000
#define IN_DIM  256
#define NH      4
#define HD      128   // NH * 32
#define NEG_SLOPE 0.2f
#define SCAN_BLOCKS ((N_NODES + 255) / 256)   // 196

// ---------------------------------------------------------------------------
// K1: LDS-tiled outer-product GEMM (ft = feat @ W) + fused head scalars +
// reparameterize. Block 256 computes 64 rows x 128 cols; thread owns 8x4.
// featT staged transposed in LDS (stride 68 -> float4-aligned, <=4-way write
// conflict only on staging); W chunk staged [32][128]. Register-prefetch of
// chunk c+1 overlaps compute on chunk c.
// ---------------------------------------------------------------------------
#define TM   64
#define KC   32
#define LDSP 68

__global__ __launch_bounds__(256) void k1_gemm_scalars(
    const float* __restrict__ feat, const float* __restrict__ W,
    const float* __restrict__ mu_src, const float* __restrict__ mu_dst,
    const float* __restrict__ lam_src,
    const float* __restrict__ eps_src, const float* __restrict__ eps_dst,
    float* __restrict__ ft_ws, float* __restrict__ z_src_ws,
    float* __restrict__ z_dst_ws,
    float* __restrict__ mu_out, float* __restrict__ lam_out)
{
    __shared__ float fT[KC][LDSP];   // 8.5 KB, transposed feat tile
    __shared__ float Wt[KC][HD];     // 16 KB

    const int t  = threadIdx.x;
    const int r0 = blockIdx.x * TM;
    const int c0 = (t & 31) * 4;     // 4 output cols
    const int rb = (t >> 5) * 8;     // 8 output rows (within tile)

    float acc[8][4];
#pragma unroll
    for (int i = 0; i < 8; ++i)
#pragma unroll
        for (int j = 0; j < 4; ++j) acc[i][j] = 0.0f;

    float4 fa[2], fw[4];

    // staging addresses (chunk-invariant parts)
    const int kk_off = 4 * (t & 7);          // k within chunk for feat load
    const int rowA   = t >> 3;               // 0..31
    const int rA = min(r0 + rowA,      N_NODES - 1);
    const int rB = min(r0 + rowA + 32, N_NODES - 1);
    const int wkr = t >> 5;                  // 0..7

#define LOAD_CHUNK(kc0)                                                        \
    do {                                                                       \
        fa[0] = *(const float4*)(feat + (size_t)rA * IN_DIM + (kc0) + kk_off); \
        fa[1] = *(const float4*)(feat + (size_t)rB * IN_DIM + (kc0) + kk_off); \
        _Pragma("unroll")                                                      \
        for (int i = 0; i < 4; ++i)                                            \
            fw[i] = *(const float4*)(W + (size_t)((kc0) + wkr + 8 * i) * HD + c0); \
    } while (0)

    LOAD_CHUNK(0);

    for (int c = 0; c < IN_DIM / KC; ++c) {
        __syncthreads();
        // store prefetched chunk to LDS
#pragma unroll
        for (int j = 0; j < 4; ++j) {
            fT[kk_off + j][rowA]      = ((const float*)&fa[0])[j];
            fT[kk_off + j][rowA + 32] = ((const float*)&fa[1])[j];
        }
#pragma unroll
        for (int i = 0; i < 4; ++i)
            *(float4*)&Wt[wkr + 8 * i][c0] = fw[i];
        __syncthreads();

        if (c + 1 < IN_DIM / KC) LOAD_CHUNK((c + 1) * KC);

#pragma unroll 8
        for (int k = 0; k < KC; ++k) {
            const float4 a0 = *(const float4*)&fT[k][rb];
            const float4 a1 = *(const float4*)&fT[k][rb + 4];
            const float4 wv = *(const float4*)&Wt[k][c0];
            const float ar[8] = {a0.x, a0.y, a0.z, a0.w, a1.x, a1.y, a1.z, a1.w};
#pragma unroll
            for (int i = 0; i < 8; ++i) {
                acc[i][0] = fmaf(ar[i], wv.x, acc[i][0]);
                acc[i][1] = fmaf(ar[i], wv.y, acc[i][1]);
                acc[i][2] = fmaf(ar[i], wv.z, acc[i][2]);
                acc[i][3] = fmaf(ar[i], wv.w, acc[i][3]);
            }
        }
    }

    // ---- store ft (coalesced float4), predicated on row bound ----
#pragma unroll
    for (int i = 0; i < 8; ++i) {
        const int row = r0 + rb + i;
        if (row < N_NODES)
            *(float4*)(ft_ws + (size_t)row * HD + c0) =
                make_float4(acc[i][0], acc[i][1], acc[i][2], acc[i][3]);
    }

    // ---- fused per-head scalars: dot over the head's 32 cols ----
    const float4 ms4 = *(const float4*)(mu_src + c0);
    const float4 md4 = *(const float4*)(mu_dst + c0);
    const float4 ls4 = *(const float4*)(lam_src + c0);
    const int h = (t & 31) >> 3;     // head of this thread's 4 cols

#pragma unroll
    for (int i = 0; i < 8; ++i) {
        float pm = acc[i][0] * ms4.x + acc[i][1] * ms4.y +
                   acc[i][2] * ms4.z + acc[i][3] * ms4.w;
        float pd = acc[i][0] * md4.x + acc[i][1] * md4.y +
                   acc[i][2] * md4.z + acc[i][3] * md4.w;
        float pl = acc[i][0] * ls4.x + acc[i][1] * ls4.y +
                   acc[i][2] * ls4.z + acc[i][3] * ls4.w;
#pragma unroll
        for (int m = 4; m >= 1; m >>= 1) {     // reduce 8-lane group
            pm += __shfl_xor(pm, m, 64);
            pd += __shfl_xor(pd, m, 64);
            pl += __shfl_xor(pl, m, 64);
        }
        if ((t & 7) == 0) {
            const int row = r0 + rb + i;
            if (row < N_NODES) {
                const float mu_s  = pm;
                const float mu_d  = pd;
                const float lam_s = pl;            // lam_d == lam_s in ref
                const float sdev  = expf(0.5f * lam_s);
                z_src_ws[row * NH + h] = eps_src[row * NH + h] * sdev + mu_s;
                z_dst_ws[row * NH + h] = eps_dst[row * NH + h] * sdev + mu_d;
                mu_out[row * NH + h]   = mu_s + mu_d;
                lam_out[row * NH + h]  = 2.0f * lam_s;
            }
        }
    }
}

// ---------------------------------------------------------------------------
__device__ __forceinline__ void edge_w(float4 zs, float4 zd, float scale,
                                       float w[4])
{
    float z[4] = {zs.x + zd.x, zs.y + zd.y, zs.z + zd.z, zs.w + zd.w};
#pragma unroll
    for (int h = 0; h < 4; ++h) {
        float v = z[h];
        v = (v >= 0.0f) ? v : NEG_SLOPE * v;   // leaky_relu
        w[h] = __expf(v * scale);
    }
}

__device__ __forceinline__ float edge_scale(float p)
{
    // clip(log(clip(log(ppmi),1,inf)),1,inf)
    const float lp = fmaxf(__logf(p), 1.0f);
    return fmaxf(__logf(lp), 1.0f);
}

// ---------------------------------------------------------------------------
// K2: dst-degree histogram only (denominator now computed in K3).
// ---------------------------------------------------------------------------
__global__ __launch_bounds__(256) void k2_hist(
    const int* __restrict__ dst, int* __restrict__ counts)
{
    const int e = blockIdx.x * 256 + threadIdx.x;
    if (e < N_EDGES) atomicAdd(&counts[dst[e]], 1);
}

// ---------------------------------------------------------------------------
// Scan: counts[N] -> exclusive offsets (3 small kernels)
// ---------------------------------------------------------------------------
__global__ __launch_bounds__(256) void k_scan_local(
    const int* __restrict__ counts, int* __restrict__ local,
    int* __restrict__ bsums)
{
    __shared__ int sh[256];
    const int t = threadIdx.x;
    const int i = blockIdx.x * 256 + t;
    const int v = (i < N_NODES) ? counts[i] : 0;
    sh[t] = v;
    __syncthreads();
#pragma unroll
    for (int off = 1; off < 256; off <<= 1) {
        int x = (t >= off) ? sh[t - off] : 0;
        __syncthreads();
        sh[t] += x;
        __syncthreads();
    }
    if (i < N_NODES) local[i] = sh[t] - v;
    if (t == 255) bsums[blockIdx.x] = sh[255];
}

__global__ __launch_bounds__(256) void k_scan_bsums(
    const int* __restrict__ bsums, int* __restrict__ bscan)
{
    __shared__ int sh[256];
    const int t = threadIdx.x;
    const int v = (t < SCAN_BLOCKS) ? bsums[t] : 0;
    sh[t] = v;
    __syncthreads();
#pragma unroll
    for (int off = 1; off < 256; off <<= 1) {
        int x = (t >= off) ? sh[t - off] : 0;
        __syncthreads();
        sh[t] += x;
        __syncthreads();
    }
    if (t < SCAN_BLOCKS) bscan[t] = sh[t] - v;
}

__global__ __launch_bounds__(256) void k_scan_add(
    const int* __restrict__ local, const int* __restrict__ bscan,
    int* __restrict__ offsets, int* __restrict__ cursor)
{
    const int i = blockIdx.x * 256 + threadIdx.x;
    if (i >= N_NODES) return;
    const int o = local[i] + bscan[blockIdx.x];
    offsets[i] = o;
    cursor[i]  = o;
}

// ---------------------------------------------------------------------------
// Scatter edges into dst-sorted order with UN-normalized weights.
// ---------------------------------------------------------------------------
__global__ __launch_bounds__(256) void k_scatter(
    const int* __restrict__ src, const int* __restrict__ dst,
    const float* __restrict__ ppmi,
    const float4* __restrict__ z_src_ws, const float4* __restrict__ z_dst_ws,
    int* __restrict__ cursor,
    int* __restrict__ esrc_sorted, float4* __restrict__ w_sorted)
{
    const int e = blockIdx.x * 256 + threadIdx.x;
    if (e >= N_EDGES) return;
    const int s  = src[e];
    const int d0 = dst[e];
    const int j  = atomicAdd(&cursor[d0], 1);

    float w[4];
    edge_w(z_src_ws[s], z_dst_ws[d0], edge_scale(ppmi[e]), w);
    esrc_sorted[j] = s;
    w_sorted[j]    = make_float4(w[0], w[1], w[2], w[3]);
}

// ---------------------------------------------------------------------------
// K3: CSR segmented reduction, one wave per dst node, lane owns float2.
// Accumulates w-weighted sum AND w-sum; divides once at the end.
// ---------------------------------------------------------------------------
__global__ __launch_bounds__(64) void k3_csr(
    const int* __restrict__ offsets, const int* __restrict__ counts,
    const int* __restrict__ esrc_sorted, const float* __restrict__ w_sorted,
    const float2* __restrict__ ft2, float2* __restrict__ rst2)
{
    const int node = blockIdx.x;
    const int lane = threadIdx.x;
    const int h    = lane >> 4;                 // head = (lane*2)/32
    const int start = offsets[node];
    const int deg   = counts[node];

    float2 acc = make_float2(0.0f, 0.0f);
    float  wsum = 0.0f;

    int s_nx = 0; float w_nx = 0.0f;
    if (deg > 0) {
        s_nx = esrc_sorted[start];
        w_nx = w_sorted[(size_t)start * 4 + h];
    }
    for (int i = 0; i < deg; ++i) {
        const int   s_cur = s_nx;
        const float w_cur = w_nx;
        if (i + 1 < deg) {
            s_nx = esrc_sorted[start + i + 1];
            w_nx = w_sorted[(size_t)(start + i + 1) * 4 + h];
        }
        const float2 f = ft2[(size_t)s_cur * 64 + lane];
        acc.x = fmaf(f.x, w_cur, acc.x);
        acc.y = fmaf(f.y, w_cur, acc.y);
        wsum += w_cur;
    }
    const float inv = (wsum > 0.0f) ? 1.0f / wsum : 0.0f;
    rst2[(size_t)node * 64 + lane] = make_float2(acc.x * inv, acc.y * inv);
}

// ---------------------------------------------------------------------------
extern "C" void kernel_launch(void* const* d_in, const int* in_sizes, int n_in,
                              void* d_out, int out_size, void* d_ws, size_t ws_size,
                              hipStream_t stream)
{
    const float* feat    = (const float*)d_in[0];
    const int*   src     = (const int*)  d_in[1];
    const int*   dst     = (const int*)  d_in[2];
    const float* ppmi    = (const float*)d_in[3];
    const float* eps_src = (const float*)d_in[4];
    const float* eps_dst = (const float*)d_in[5];
    const float* W       = (const float*)d_in[6];
    const float* mu_src  = (const float*)d_in[7];
    const float* mu_dst  = (const float*)d_in[8];
    const float* lam_src = (const float*)d_in[9];
    // d_in[10] = lam_dst: unused by the reference math

    float* out     = (float*)d_out;
    float* rst     = out;                                 // N*HD
    float* mu_out  = out + (size_t)N_NODES * HD;          // N*NH
    float* lam_out = mu_out + (size_t)N_NODES * NH;       // N*NH

    float* ws      = (float*)d_ws;
    float* ft_ws   = ws;                                   // N*HD (25.6 MB)
    float* zs_ws   = ft_ws + (size_t)N_NODES * HD;         // N*NH
    float* zd_ws   = zs_ws + (size_t)N_NODES * NH;         // N*NH
    int*   counts  = (int*)(zd_ws + (size_t)N_NODES * NH); // N  (zeroed)
    int*   local   = counts + N_NODES;                     // N
    int*   offsets = local + N_NODES;                      // N
    int*   cursor  = offsets + N_NODES;                    // N
    int*   bsums   = cursor + N_NODES;                     // 256
    int*   bscan   = bsums + 256;                          // 256
    int*   esrc_s  = bscan + 256;                          // E (3.2 MB)
    float* w_sort  = (float*)(esrc_s + N_EDGES);           // E*NH (12.8 MB)

    hipMemsetAsync(counts, 0, N_NODES * sizeof(int), stream);

    k1_gemm_scalars<<<(N_NODES + TM - 1) / TM, 256, 0, stream>>>(
        feat, W, mu_src, mu_dst, lam_src, eps_src, eps_dst,
        ft_ws, zs_ws, zd_ws, mu_out, lam_out);

    k2_hist<<<(N_EDGES + 255) / 256, 256, 0, stream>>>(dst, counts);

    k_scan_local<<<SCAN_BLOCKS, 256, 0, stream>>>(counts, local, bsums);
    k_scan_bsums<<<1, 256, 0, stream>>>(bsums, bscan);
    k_scan_add<<<SCAN_BLOCKS, 256, 0, stream>>>(local, bscan, offsets, cursor);

    k_scatter<<<(N_EDGES + 255) / 256, 256, 0, stream>>>(
        src, dst, ppmi, (const float4*)zs_ws, (const float4*)zd_ws,
        cursor, esrc_s, (float4*)w_sort);

    k3_csr<<<N_NODES, 64, 0, stream>>>(
        offsets, counts, esrc_s, w_sort, (const float2*)ft_ws, (float2*)rst);
}

// Round 4
// 306.790 us; speedup vs baseline: 6.1561x; 1.0928x over previous
//
#include <hip/hip_runtime.h>

#define N_NODES 50000
#define N_EDGES 800000
#define IN_DIM  256
#define NH      4
#define HD      128   // NH * 32
#define NEG_SLOPE 0.2f
#define SCAN_BLOCKS ((N_NODES + 255) / 256)   // 196

// RNE float -> bf16 bits
__device__ __forceinline__ unsigned short f2bf(float f)
{
    unsigned int u = __float_as_uint(f);
    u += 0x7fffu + ((u >> 16) & 1u);
    return (unsigned short)(u >> 16);
}
__device__ __forceinline__ float bf2f(unsigned int bits16)
{
    return __uint_as_float(bits16 << 16);
}

// ---------------------------------------------------------------------------
// K1: LDS-tiled outer-product GEMM (ft = feat @ W) + fused head scalars +
// reparameterize. Block 256 computes 64 rows x 128 cols; thread owns 8x4.
// ft is written to workspace in bf16. Epilogue scalars staged in LDS (reuse
// of the dead fT buffer) and written coalesced.
// ---------------------------------------------------------------------------
#define TM   64
#define KC   32
#define LDSP 68

__global__ __launch_bounds__(256) void k1_gemm_scalars(
    const float* __restrict__ feat, const float* __restrict__ W,
    const float* __restrict__ mu_src, const float* __restrict__ mu_dst,
    const float* __restrict__ lam_src,
    const float* __restrict__ eps_src, const float* __restrict__ eps_dst,
    unsigned short* __restrict__ ft_bf, float* __restrict__ z_src_ws,
    float* __restrict__ z_dst_ws,
    float* __restrict__ mu_out, float* __restrict__ lam_out)
{
    __shared__ float fT[KC][LDSP];   // 8.5 KB, transposed feat tile
    __shared__ float Wt[KC][HD];     // 16 KB

    const int t  = threadIdx.x;
    const int r0 = blockIdx.x * TM;
    const int c0 = (t & 31) * 4;     // 4 output cols
    const int rb = (t >> 5) * 8;     // 8 output rows (within tile)

    float acc[8][4];
#pragma unroll
    for (int i = 0; i < 8; ++i)
#pragma unroll
        for (int j = 0; j < 4; ++j) acc[i][j] = 0.0f;

    float4 fa[2], fw[4];

    const int kk_off = 4 * (t & 7);          // k within chunk for feat load
    const int rowA   = t >> 3;               // 0..31
    const int rA = min(r0 + rowA,      N_NODES - 1);
    const int rB = min(r0 + rowA + 32, N_NODES - 1);
    const int wkr = t >> 5;                  // 0..7

#define LOAD_CHUNK(kc0)                                                        \
    do {                                                                       \
        fa[0] = *(const float4*)(feat + (size_t)rA * IN_DIM + (kc0) + kk_off); \
        fa[1] = *(const float4*)(feat + (size_t)rB * IN_DIM + (kc0) + kk_off); \
        _Pragma("unroll")                                                      \
        for (int i = 0; i < 4; ++i)                                            \
            fw[i] = *(const float4*)(W + (size_t)((kc0) + wkr + 8 * i) * HD + c0); \
    } while (0)

    LOAD_CHUNK(0);

    for (int c = 0; c < IN_DIM / KC; ++c) {
        __syncthreads();
#pragma unroll
        for (int j = 0; j < 4; ++j) {
            fT[kk_off + j][rowA]      = ((const float*)&fa[0])[j];
            fT[kk_off + j][rowA + 32] = ((const float*)&fa[1])[j];
        }
#pragma unroll
        for (int i = 0; i < 4; ++i)
            *(float4*)&Wt[wkr + 8 * i][c0] = fw[i];
        __syncthreads();

        if (c + 1 < IN_DIM / KC) LOAD_CHUNK((c + 1) * KC);

#pragma unroll 8
        for (int k = 0; k < KC; ++k) {
            const float4 a0 = *(const float4*)&fT[k][rb];
            const float4 a1 = *(const float4*)&fT[k][rb + 4];
            const float4 wv = *(const float4*)&Wt[k][c0];
            const float ar[8] = {a0.x, a0.y, a0.z, a0.w, a1.x, a1.y, a1.z, a1.w};
#pragma unroll
            for (int i = 0; i < 8; ++i) {
                acc[i][0] = fmaf(ar[i], wv.x, acc[i][0]);
                acc[i][1] = fmaf(ar[i], wv.y, acc[i][1]);
                acc[i][2] = fmaf(ar[i], wv.z, acc[i][2]);
                acc[i][3] = fmaf(ar[i], wv.w, acc[i][3]);
            }
        }
    }

    // ---- store ft in bf16 (8B/lane, coalesced), predicated on row bound ----
#pragma unroll
    for (int i = 0; i < 8; ++i) {
        const int row = r0 + rb + i;
        if (row < N_NODES) {
            ushort4 us;
            us.x = f2bf(acc[i][0]); us.y = f2bf(acc[i][1]);
            us.z = f2bf(acc[i][2]); us.w = f2bf(acc[i][3]);
            *(ushort4*)(ft_bf + (size_t)row * HD + c0) = us;
        }
    }

    // ---- fused per-head scalars: dot over the head's 32 cols ----
    const float4 ms4 = *(const float4*)(mu_src + c0);
    const float4 md4 = *(const float4*)(mu_dst + c0);
    const float4 ls4 = *(const float4*)(lam_src + c0);
    const int h = (t & 31) >> 3;     // head of this thread's 4 cols

    // reuse dead fT as scalar staging: [row_in_tile*4 + h], 3 arrays of 256
    float* sh_m = &fT[0][0];         // mu_s
    float* sh_d = sh_m + 256;        // mu_d
    float* sh_l = sh_d + 256;        // lam_s
    __syncthreads();                 // all waves done reading fT/Wt

#pragma unroll
    for (int i = 0; i < 8; ++i) {
        float pm = acc[i][0] * ms4.x + acc[i][1] * ms4.y +
                   acc[i][2] * ms4.z + acc[i][3] * ms4.w;
        float pd = acc[i][0] * md4.x + acc[i][1] * md4.y +
                   acc[i][2] * md4.z + acc[i][3] * md4.w;
        float pl = acc[i][0] * ls4.x + acc[i][1] * ls4.y +
                   acc[i][2] * ls4.z + acc[i][3] * ls4.w;
#pragma unroll
        for (int m = 4; m >= 1; m >>= 1) {     // reduce 8-lane group
            pm += __shfl_xor(pm, m, 64);
            pd += __shfl_xor(pd, m, 64);
            pl += __shfl_xor(pl, m, 64);
        }
        if ((t & 7) == 0) {
            const int idx = (rb + i) * NH + h;   // 0..255
            sh_m[idx] = pm;
            sh_d[idx] = pd;
            sh_l[idx] = pl;
        }
    }
    __syncthreads();

    // ---- coalesced epilogue: thread t owns flat element r0*4 + t ----
    {
        const int gidx = r0 * NH + t;            // global [N*NH] index
        const int row  = r0 + (t >> 2);
        if (row < N_NODES) {
            const float mu_s  = sh_m[t];
            const float mu_d  = sh_d[t];
            const float lam_s = sh_l[t];         // lam_d == lam_s in ref
            const float sdev  = expf(0.5f * lam_s);
            z_src_ws[gidx] = eps_src[gidx] * sdev + mu_s;
            z_dst_ws[gidx] = eps_dst[gidx] * sdev + mu_d;
            mu_out[gidx]   = mu_s + mu_d;
            lam_out[gidx]  = 2.0f * lam_s;
        }
    }
}

// ---------------------------------------------------------------------------
__device__ __forceinline__ void edge_w(float4 zs, float4 zd, float scale,
                                       float w[4])
{
    float z[4] = {zs.x + zd.x, zs.y + zd.y, zs.z + zd.z, zs.w + zd.w};
#pragma unroll
    for (int h = 0; h < 4; ++h) {
        float v = z[h];
        v = (v >= 0.0f) ? v : NEG_SLOPE * v;   // leaky_relu
        w[h] = __expf(v * scale);
    }
}

__device__ __forceinline__ float edge_scale(float p)
{
    const float lp = fmaxf(__logf(p), 1.0f);
    return fmaxf(__logf(lp), 1.0f);
}

// ---------------------------------------------------------------------------
// K2: dst-degree histogram.
// ---------------------------------------------------------------------------
__global__ __launch_bounds__(256) void k2_hist(
    const int* __restrict__ dst, int* __restrict__ counts)
{
    const int e = blockIdx.x * 256 + threadIdx.x;
    if (e < N_EDGES) atomicAdd(&counts[dst[e]], 1);
}

// ---------------------------------------------------------------------------
// Scan: counts[N] -> exclusive offsets
// ---------------------------------------------------------------------------
__global__ __launch_bounds__(256) void k_scan_local(
    const int* __restrict__ counts, int* __restrict__ local,
    int* __restrict__ bsums)
{
    __shared__ int sh[256];
    const int t = threadIdx.x;
    const int i = blockIdx.x * 256 + t;
    const int v = (i < N_NODES) ? counts[i] : 0;
    sh[t] = v;
    __syncthreads();
#pragma unroll
    for (int off = 1; off < 256; off <<= 1) {
        int x = (t >= off) ? sh[t - off] : 0;
        __syncthreads();
        sh[t] += x;
        __syncthreads();
    }
    if (i < N_NODES) local[i] = sh[t] - v;
    if (t == 255) bsums[blockIdx.x] = sh[255];
}

__global__ __launch_bounds__(256) void k_scan_bsums(
    const int* __restrict__ bsums, int* __restrict__ bscan)
{
    __shared__ int sh[256];
    const int t = threadIdx.x;
    const int v = (t < SCAN_BLOCKS) ? bsums[t] : 0;
    sh[t] = v;
    __syncthreads();
#pragma unroll
    for (int off = 1; off < 256; off <<= 1) {
        int x = (t >= off) ? sh[t - off] : 0;
        __syncthreads();
        sh[t] += x;
        __syncthreads();
    }
    if (t < SCAN_BLOCKS) bscan[t] = sh[t] - v;
}

__global__ __launch_bounds__(256) void k_scan_add(
    const int* __restrict__ local, const int* __restrict__ bscan,
    int* __restrict__ offsets, int* __restrict__ cursor)
{
    const int i = blockIdx.x * 256 + threadIdx.x;
    if (i >= N_NODES) return;
    const int o = local[i] + bscan[blockIdx.x];
    offsets[i] = o;
    cursor[i]  = o;
}

// ---------------------------------------------------------------------------
// Scatter edges into dst-sorted order: ONE 16B record per edge
//   rec = {src, w0|w1 (bf16x2), w2|w3 (bf16x2), unused}
// ---------------------------------------------------------------------------
__global__ __launch_bounds__(256) void k_scatter(
    const int* __restrict__ src, const int* __restrict__ dst,
    const float* __restrict__ ppmi,
    const float4* __restrict__ z_src_ws, const float4* __restrict__ z_dst_ws,
    int* __restrict__ cursor, int4* __restrict__ rec_sorted)
{
    const int e = blockIdx.x * 256 + threadIdx.x;
    if (e >= N_EDGES) return;
    const int s  = src[e];
    const int d0 = dst[e];
    const int j  = atomicAdd(&cursor[d0], 1);

    float w[4];
    edge_w(z_src_ws[s], z_dst_ws[d0], edge_scale(ppmi[e]), w);
    int4 rec;
    rec.x = s;
    rec.y = (int)((unsigned)f2bf(w[0]) | ((unsigned)f2bf(w[1]) << 16));
    rec.z = (int)((unsigned)f2bf(w[2]) | ((unsigned)f2bf(w[3]) << 16));
    rec.w = 0;
    rec_sorted[j] = rec;
}

// ---------------------------------------------------------------------------
// K3: CSR segmented reduction. One wave per dst node; lane owns 2 bf16 cols
// (4B gather per lane -> 256B per edge). Accumulate fp32, divide once.
// ---------------------------------------------------------------------------
__global__ __launch_bounds__(64) void k3_csr(
    const int* __restrict__ offsets, const int* __restrict__ counts,
    const int4* __restrict__ rec_sorted,
    const unsigned int* __restrict__ ft_u32, float2* __restrict__ rst2)
{
    const int node = blockIdx.x;
    const int lane = threadIdx.x;
    const int h    = lane >> 4;                 // head = (2*lane)/32
    const int start = offsets[node];
    const int deg   = counts[node];

    float2 acc = make_float2(0.0f, 0.0f);
    float  wsum = 0.0f;

    int4 rec_nx = make_int4(0, 0, 0, 0);
    if (deg > 0) rec_nx = rec_sorted[start];

    for (int i = 0; i < deg; ++i) {
        const int4 rec = rec_nx;
        if (i + 1 < deg) rec_nx = rec_sorted[start + i + 1];

        const unsigned pair = (h < 2) ? (unsigned)rec.y : (unsigned)rec.z;
        const float w = bf2f((h & 1) ? (pair >> 16) : (pair & 0xffffu));

        const unsigned fbits = ft_u32[(size_t)rec.x * (HD / 2) + lane];
        acc.x = fmaf(bf2f(fbits & 0xffffu), w, acc.x);
        acc.y = fmaf(bf2f(fbits >> 16),     w, acc.y);
        wsum += w;
    }
    const float inv = (wsum > 0.0f) ? 1.0f / wsum : 0.0f;
    rst2[(size_t)node * (HD / 2) + lane] = make_float2(acc.x * inv, acc.y * inv);
}

// ---------------------------------------------------------------------------
extern "C" void kernel_launch(void* const* d_in, const int* in_sizes, int n_in,
                              void* d_out, int out_size, void* d_ws, size_t ws_size,
                              hipStream_t stream)
{
    const float* feat    = (const float*)d_in[0];
    const int*   src     = (const int*)  d_in[1];
    const int*   dst     = (const int*)  d_in[2];
    const float* ppmi    = (const float*)d_in[3];
    const float* eps_src = (const float*)d_in[4];
    const float* eps_dst = (const float*)d_in[5];
    const float* W       = (const float*)d_in[6];
    const float* mu_src  = (const float*)d_in[7];
    const float* mu_dst  = (const float*)d_in[8];
    const float* lam_src = (const float*)d_in[9];
    // d_in[10] = lam_dst: unused by the reference math

    float* out     = (float*)d_out;
    float* rst     = out;                                 // N*HD
    float* mu_out  = out + (size_t)N_NODES * HD;          // N*NH
    float* lam_out = mu_out + (size_t)N_NODES * NH;       // N*NH

    // workspace layout (16B-aligned first)
    char* wsb = (char*)d_ws;
    int4*           rec_s  = (int4*)wsb;                              // E*16B
    unsigned short* ft_bf  = (unsigned short*)(wsb + (size_t)N_EDGES * 16); // N*HD*2B
    float*          zs_ws  = (float*)((char*)ft_bf + (size_t)N_NODES * HD * 2);
    float*          zd_ws  = zs_ws + (size_t)N_NODES * NH;
    int*            counts = (int*)(zd_ws + (size_t)N_NODES * NH);
    int*            local  = counts + N_NODES;
    int*            offsets= local + N_NODES;
    int*            cursor = offsets + N_NODES;
    int*            bsums  = cursor + N_NODES;
    int*            bscan  = bsums + 256;

    hipMemsetAsync(counts, 0, N_NODES * sizeof(int), stream);

    k1_gemm_scalars<<<(N_NODES + TM - 1) / TM, 256, 0, stream>>>(
        feat, W, mu_src, mu_dst, lam_src, eps_src, eps_dst,
        ft_bf, zs_ws, zd_ws, mu_out, lam_out);

    k2_hist<<<(N_EDGES + 255) / 256, 256, 0, stream>>>(dst, counts);

    k_scan_local<<<SCAN_BLOCKS, 256, 0, stream>>>(counts, local, bsums);
    k_scan_bsums<<<1, 256, 0, stream>>>(bsums, bscan);
    k_scan_add<<<SCAN_BLOCKS, 256, 0, stream>>>(local, bscan, offsets, cursor);

    k_scatter<<<(N_EDGES + 255) / 256, 256, 0, stream>>>(
        src, dst, ppmi, (const float4*)zs_ws, (const float4*)zd_ws,
        cursor, rec_s);

    k3_csr<<<N_NODES, 64, 0, stream>>>(
        offsets, counts, rec_s, (const unsigned int*)ft_bf, (float2*)rst);
}

// Round 6
// 262.214 us; speedup vs baseline: 7.2027x; 1.1700x over previous
//
#include <hip/hip_runtime.h>

#define N_NODES 50000
#define N_EDGES 800000
#define IN_DIM  256
#define NH      4
#define HD      128   // NH * 32
#define NEG_SLOPE 0.2f
#define SCAN_BLOCKS ((N_NODES + 255) / 256)   // 196

typedef short          v8s __attribute__((ext_vector_type(8)));
typedef float          v4f __attribute__((ext_vector_type(4)));
typedef unsigned short us8 __attribute__((ext_vector_type(8)));

// RNE float -> bf16 bits
__device__ __forceinline__ unsigned short f2bf(float f)
{
    unsigned int u = __float_as_uint(f);
    u += 0x7fffu + ((u >> 16) & 1u);
    return (unsigned short)(u >> 16);
}
__device__ __forceinline__ float bf2f(unsigned int bits16)
{
    return __uint_as_float(bits16 << 16);
}

// ---------------------------------------------------------------------------
// K0: W [256k x 128n] fp32 -> Wt_bf [128n x 256k] bf16 (transpose+convert).
// ---------------------------------------------------------------------------
__global__ __launch_bounds__(256) void k0_wt(
    const float* __restrict__ W, unsigned short* __restrict__ Wt_bf)
{
    const int idx = blockIdx.x * 256 + threadIdx.x;   // grid covers 128*256
    const int n = idx >> 8;          // 0..127
    const int k = idx & 255;         // 0..255
    Wt_bf[n * IN_DIM + k] = f2bf(W[(size_t)k * HD + n]);
}

// ---------------------------------------------------------------------------
// K1: MFMA bf16 GEMM  ft_bf[N x 128] = feat[N x 256] @ W.
// 128x128 block tile, BK=32, 4 waves x (32 rows x 128 cols), 2x8 frags of
// 16x16x32. feat converted fp32->bf16 during LDS staging; W from Wt_bf.
// ---------------------------------------------------------------------------
#define AS 40            // LDS row stride in shorts (80 B = 5*16)
#define CS 136           // C tile row stride in shorts (272 B = 17*16)

__global__ __launch_bounds__(256) void k1_mfma(
    const float* __restrict__ feat, const unsigned short* __restrict__ Wt_bf,
    unsigned short* __restrict__ ft_bf)
{
    __shared__ ushort smem[17408];   // A(5120)+B(5120) shorts / C(17408) shorts
    ushort* A_sh = smem;             // [128][AS]
    ushort* B_sh = smem + 128 * AS;  // [128][AS]

    const int t    = threadIdx.x;
    const int lane = t & 63;
    const int wv   = t >> 6;
    const int r0   = blockIdx.x * 128;

    // staging coords
    const int arow = t >> 3;            // 0..31 (+32p)
    const int akk  = (t & 7) * 4;       // k within chunk
    int rA[4];
#pragma unroll
    for (int p = 0; p < 4; ++p) rA[p] = min(r0 + arow + 32 * p, N_NODES - 1);
    const int bn  = t >> 2;             // 0..63 (+64p)
    const int bk8 = (t & 3) * 8;

    float4 fa[4];
    us8    fb[2];

#define LOADC(kc0)                                                              \
    do {                                                                        \
        _Pragma("unroll")                                                       \
        for (int p = 0; p < 4; ++p)                                             \
            fa[p] = *(const float4*)(feat + (size_t)rA[p] * IN_DIM + (kc0) + akk); \
        _Pragma("unroll")                                                       \
        for (int p = 0; p < 2; ++p)                                             \
            fb[p] = *(const us8*)(Wt_bf + (size_t)(bn + 64 * p) * IN_DIM + (kc0) + bk8); \
    } while (0)

    v4f acc[2][8];
#pragma unroll
    for (int i = 0; i < 2; ++i)
#pragma unroll
        for (int j = 0; j < 8; ++j) acc[i][j] = (v4f)(0.0f);

    const int frow = lane & 15;
    const int fq   = lane >> 4;

    LOADC(0);

    for (int c = 0; c < IN_DIM / 32; ++c) {
        __syncthreads();
        // store staged chunk to LDS (fp32 -> bf16 for A)
#pragma unroll
        for (int p = 0; p < 4; ++p) {
            ushort4 u;
            u.x = f2bf(fa[p].x); u.y = f2bf(fa[p].y);
            u.z = f2bf(fa[p].z); u.w = f2bf(fa[p].w);
            *(ushort4*)(A_sh + (arow + 32 * p) * AS + akk) = u;
        }
#pragma unroll
        for (int p = 0; p < 2; ++p)
            *(us8*)(B_sh + (bn + 64 * p) * AS + bk8) = fb[p];
        __syncthreads();

        if (c + 1 < IN_DIM / 32) LOADC((c + 1) * 32);

        // fragments + MFMA
        v8s a0 = *(const v8s*)(A_sh + (wv * 32 + frow) * AS + fq * 8);
        v8s a1 = *(const v8s*)(A_sh + (wv * 32 + 16 + frow) * AS + fq * 8);
        v8s bfr[8];
#pragma unroll
        for (int nf = 0; nf < 8; ++nf)
            bfr[nf] = *(const v8s*)(B_sh + (nf * 16 + frow) * AS + fq * 8);
#pragma unroll
        for (int nf = 0; nf < 8; ++nf) {
            acc[0][nf] = __builtin_amdgcn_mfma_f32_16x16x32_bf16(
                a0, bfr[nf], acc[0][nf], 0, 0, 0);
            acc[1][nf] = __builtin_amdgcn_mfma_f32_16x16x32_bf16(
                a1, bfr[nf], acc[1][nf], 0, 0, 0);
        }
    }

    // ---- epilogue: per-wave C tile through LDS, coalesced bf16 store ----
    __syncthreads();                       // A/B reads done; reuse LDS as C
    ushort* Cw = smem + wv * (32 * CS);
#pragma unroll
    for (int mf = 0; mf < 2; ++mf)
#pragma unroll
        for (int nf = 0; nf < 8; ++nf)
#pragma unroll
            for (int r = 0; r < 4; ++r)
                Cw[(mf * 16 + fq * 4 + r) * CS + nf * 16 + frow] =
                    f2bf(acc[mf][nf][r]);
    __syncthreads();

    // 16 lanes x us8 = full 128-short row; 4 rows/iter x 8 iters = 32 rows
#pragma unroll
    for (int p = 0; p < 8; ++p) {
        const int row_l = (lane >> 4) + 4 * p;
        const int colv  = (lane & 15) * 8;
        const us8 val = *(const us8*)(Cw + row_l * CS + colv);
        const int grow = r0 + wv * 32 + row_l;
        if (grow < N_NODES)
            *(us8*)(ft_bf + (size_t)grow * HD + colv) = val;
    }
}

// ---------------------------------------------------------------------------
// K1b: per-(node,head) scalars from ft_bf + reparameterize. Fully coalesced.
// ---------------------------------------------------------------------------
__global__ __launch_bounds__(256) void k1b_scalars(
    const unsigned short* __restrict__ ft_bf,
    const float* __restrict__ mu_src, const float* __restrict__ mu_dst,
    const float* __restrict__ lam_src,
    const float* __restrict__ eps_src, const float* __restrict__ eps_dst,
    float* __restrict__ z_src_ws, float* __restrict__ z_dst_ws,
    float* __restrict__ mu_out, float* __restrict__ lam_out)
{
    const int g = blockIdx.x * 256 + threadIdx.x;    // (row, head) flat
    if (g >= N_NODES * NH) return;
    const int row = g >> 2;
    const int h   = g & 3;

    const unsigned short* fr = ft_bf + (size_t)row * HD + h * 32;
    const float* ms = mu_src + h * 32;
    const float* md = mu_dst + h * 32;
    const float* ls = lam_src + h * 32;

    float pm = 0.0f, pd = 0.0f, pl = 0.0f;
#pragma unroll
    for (int v = 0; v < 4; ++v) {
        const us8 u = *(const us8*)(fr + v * 8);
#pragma unroll
        for (int j = 0; j < 8; ++j) {
            const float f = bf2f(u[j]);
            const int   i = v * 8 + j;
            pm = fmaf(f, ms[i], pm);
            pd = fmaf(f, md[i], pd);
            pl = fmaf(f, ls[i], pl);
        }
    }
    const float sdev = expf(0.5f * pl);
    z_src_ws[g] = eps_src[g] * sdev + pm;
    z_dst_ws[g] = eps_dst[g] * sdev + pd;
    mu_out[g]   = pm + pd;
    lam_out[g]  = 2.0f * pl;     // lam_d == lam_s in reference
}

// ---------------------------------------------------------------------------
__device__ __forceinline__ void edge_w(float4 zs, float4 zd, float scale,
                                       float w[4])
{
    float z[4] = {zs.x + zd.x, zs.y + zd.y, zs.z + zd.z, zs.w + zd.w};
#pragma unroll
    for (int h = 0; h < 4; ++h) {
        float v = z[h];
        v = (v >= 0.0f) ? v : NEG_SLOPE * v;   // leaky_relu
        w[h] = __expf(v * scale);
    }
}

__device__ __forceinline__ float edge_scale(float p)
{
    const float lp = fmaxf(__logf(p), 1.0f);
    return fmaxf(__logf(lp), 1.0f);
}

// ---------------------------------------------------------------------------
__global__ __launch_bounds__(256) void k2_hist(
    const int* __restrict__ dst, int* __restrict__ counts)
{
    const int e = blockIdx.x * 256 + threadIdx.x;
    if (e < N_EDGES) atomicAdd(&counts[dst[e]], 1);
}

// ---------------------------------------------------------------------------
__global__ __launch_bounds__(256) void k_scan_local(
    const int* __restrict__ counts, int* __restrict__ local,
    int* __restrict__ bsums)
{
    __shared__ int sh[256];
    const int t = threadIdx.x;
    const int i = blockIdx.x * 256 + t;
    const int v = (i < N_NODES) ? counts[i] : 0;
    sh[t] = v;
    __syncthreads();
#pragma unroll
    for (int off = 1; off < 256; off <<= 1) {
        int x = (t >= off) ? sh[t - off] : 0;
        __syncthreads();
        sh[t] += x;
        __syncthreads();
    }
    if (i < N_NODES) local[i] = sh[t] - v;
    if (t == 255) bsums[blockIdx.x] = sh[255];
}

__global__ __launch_bounds__(256) void k_scan_bsums(
    const int* __restrict__ bsums, int* __restrict__ bscan)
{
    __shared__ int sh[256];
    const int t = threadIdx.x;
    const int v = (t < SCAN_BLOCKS) ? bsums[t] : 0;
    sh[t] = v;
    __syncthreads();
#pragma unroll
    for (int off = 1; off < 256; off <<= 1) {
        int x = (t >= off) ? sh[t - off] : 0;
        __syncthreads();
        sh[t] += x;
        __syncthreads();
    }
    if (t < SCAN_BLOCKS) bscan[t] = sh[t] - v;
}

__global__ __launch_bounds__(256) void k_scan_add(
    const int* __restrict__ local, const int* __restrict__ bscan,
    int* __restrict__ offsets, int* __restrict__ cursor)
{
    const int i = blockIdx.x * 256 + threadIdx.x;
    if (i >= N_NODES) return;
    const int o = local[i] + bscan[blockIdx.x];
    offsets[i] = o;
    cursor[i]  = o;
}

// ---------------------------------------------------------------------------
// Scatter edges into dst-sorted order: ONE 16B record per edge
// ---------------------------------------------------------------------------
__global__ __launch_bounds__(256) void k_scatter(
    const int* __restrict__ src, const int* __restrict__ dst,
    const float* __restrict__ ppmi,
    const float4* __restrict__ z_src_ws, const float4* __restrict__ z_dst_ws,
    int* __restrict__ cursor, int4* __restrict__ rec_sorted)
{
    const int e = blockIdx.x * 256 + threadIdx.x;
    if (e >= N_EDGES) return;
    const int s  = src[e];
    const int d0 = dst[e];
    const int j  = atomicAdd(&cursor[d0], 1);

    float w[4];
    edge_w(z_src_ws[s], z_dst_ws[d0], edge_scale(ppmi[e]), w);
    int4 rec;
    rec.x = s;
    rec.y = (int)((unsigned)f2bf(w[0]) | ((unsigned)f2bf(w[1]) << 16));
    rec.z = (int)((unsigned)f2bf(w[2]) | ((unsigned)f2bf(w[3]) << 16));
    rec.w = 0;
    rec_sorted[j] = rec;
}

// ---------------------------------------------------------------------------
// K3: CSR segmented reduction, unrolled x2 with independent gather chains.
// ---------------------------------------------------------------------------
__global__ __launch_bounds__(64) void k3_csr(
    const int* __restrict__ offsets, const int* __restrict__ counts,
    const int4* __restrict__ rec_sorted,
    const unsigned int* __restrict__ ft_u32, float2* __restrict__ rst2)
{
    const int node = blockIdx.x;
    const int lane = threadIdx.x;
    const int h    = lane >> 4;                 // head = (2*lane)/32
    const int start = offsets[node];
    const int end   = start + counts[node];

    float2 acc0 = make_float2(0.0f, 0.0f);
    float2 acc1 = make_float2(0.0f, 0.0f);
    float  wsum = 0.0f;

    int i = start;
    for (; i + 1 < end; i += 2) {
        const int4 r0 = rec_sorted[i];
        const int4 r1 = rec_sorted[i + 1];
        const unsigned f0 = ft_u32[(size_t)r0.x * (HD / 2) + lane];
        const unsigned f1 = ft_u32[(size_t)r1.x * (HD / 2) + lane];
        const unsigned p0 = (h < 2) ? (unsigned)r0.y : (unsigned)r0.z;
        const unsigned p1 = (h < 2) ? (unsigned)r1.y : (unsigned)r1.z;
        const float w0 = bf2f((h & 1) ? (p0 >> 16) : (p0 & 0xffffu));
        const float w1 = bf2f((h & 1) ? (p1 >> 16) : (p1 & 0xffffu));
        acc0.x = fmaf(bf2f(f0 & 0xffffu), w0, acc0.x);
        acc0.y = fmaf(bf2f(f0 >> 16),     w0, acc0.y);
        acc1.x = fmaf(bf2f(f1 & 0xffffu), w1, acc1.x);
        acc1.y = fmaf(bf2f(f1 >> 16),     w1, acc1.y);
        wsum += w0 + w1;
    }
    if (i < end) {
        const int4 r0 = rec_sorted[i];
        const unsigned f0 = ft_u32[(size_t)r0.x * (HD / 2) + lane];
        const unsigned p0 = (h < 2) ? (unsigned)r0.y : (unsigned)r0.z;
        const float w0 = bf2f((h & 1) ? (p0 >> 16) : (p0 & 0xffffu));
        acc0.x = fmaf(bf2f(f0 & 0xffffu), w0, acc0.x);
        acc0.y = fmaf(bf2f(f0 >> 16),     w0, acc0.y);
        wsum += w0;
    }
    acc0.x += acc1.x;
    acc0.y += acc1.y;
    const float inv = (wsum > 0.0f) ? 1.0f / wsum : 0.0f;
    rst2[(size_t)node * (HD / 2) + lane] =
        make_float2(acc0.x * inv, acc0.y * inv);
}

// ---------------------------------------------------------------------------
extern "C" void kernel_launch(void* const* d_in, const int* in_sizes, int n_in,
                              void* d_out, int out_size, void* d_ws, size_t ws_size,
                              hipStream_t stream)
{
    const float* feat    = (const float*)d_in[0];
    const int*   src     = (const int*)  d_in[1];
    const int*   dst     = (const int*)  d_in[2];
    const float* ppmi    = (const float*)d_in[3];
    const float* eps_src = (const float*)d_in[4];
    const float* eps_dst = (const float*)d_in[5];
    const float* W       = (const float*)d_in[6];
    const float* mu_src  = (const float*)d_in[7];
    const float* mu_dst  = (const float*)d_in[8];
    const float* lam_src = (const float*)d_in[9];
    // d_in[10] = lam_dst: unused by the reference math

    float* out     = (float*)d_out;
    float* rst     = out;                                 // N*HD
    float* mu_out  = out + (size_t)N_NODES * HD;          // N*NH
    float* lam_out = mu_out + (size_t)N_NODES * NH;       // N*NH

    // workspace layout (16B-aligned first)
    char* wsb = (char*)d_ws;
    int4*           rec_s  = (int4*)wsb;                                   // E*16B
    unsigned short* ft_bf  = (unsigned short*)(wsb + (size_t)N_EDGES * 16);// N*HD*2
    unsigned short* Wt_bf  = ft_bf + (size_t)N_NODES * HD;                 // 128*256
    float*          zs_ws  = (float*)(Wt_bf + (size_t)HD * IN_DIM);
    float*          zd_ws  = zs_ws + (size_t)N_NODES * NH;
    int*            counts = (int*)(zd_ws + (size_t)N_NODES * NH);
    int*            local  = counts + N_NODES;
    int*            offsets= local + N_NODES;
    int*            cursor = offsets + N_NODES;
    int*            bsums  = cursor + N_NODES;
    int*            bscan  = bsums + 256;

    hipMemsetAsync(counts, 0, N_NODES * sizeof(int), stream);

    k0_wt<<<(HD * IN_DIM) / 256, 256, 0, stream>>>(W, Wt_bf);

    k1_mfma<<<(N_NODES + 127) / 128, 256, 0, stream>>>(feat, Wt_bf, ft_bf);

    k1b_scalars<<<(N_NODES * NH + 255) / 256, 256, 0, stream>>>(
        ft_bf, mu_src, mu_dst, lam_src, eps_src, eps_dst,
        zs_ws, zd_ws, mu_out, lam_out);

    k2_hist<<<(N_EDGES + 255) / 256, 256, 0, stream>>>(dst, counts);

    k_scan_local<<<SCAN_BLOCKS, 256, 0, stream>>>(counts, local, bsums);
    k_scan_bsums<<<1, 256, 0, stream>>>(bsums, bscan);
    k_scan_add<<<SCAN_BLOCKS, 256, 0, stream>>>(local, bscan, offsets, cursor);

    k_scatter<<<(N_EDGES + 255) / 256, 256, 0, stream>>>(
        src, dst, ppmi, (const float4*)zs_ws, (const float4*)zd_ws,
        cursor, rec_s);

    k3_csr<<<N_NODES, 64, 0, stream>>>(
        offsets, counts, rec_s, (const unsigned int*)ft_bf, (float2*)rst);
}

// Round 7
// 257.962 us; speedup vs baseline: 7.3214x; 1.0165x over previous
//
#include <hip/hip_runtime.h>

#define N_NODES 50000
#define N_EDGES 800000
#define IN_DIM  256
#define NH      4
#define HD      128   // NH * 32
#define NEG_SLOPE 0.2f
#define SCAN_BLOCKS ((N_NODES + 255) / 256)    // 196
#define HIST_BLOCKS ((N_EDGES + 255) / 256)    // 3125
#define WT_BLOCKS   ((HD * IN_DIM) / 256)      // 128
#define K1B_BLOCKS  ((N_NODES * NH + 255) / 256) // 782

typedef short          v8s __attribute__((ext_vector_type(8)));
typedef float          v4f __attribute__((ext_vector_type(4)));
typedef unsigned short us8 __attribute__((ext_vector_type(8)));

// RNE float -> bf16 bits
__device__ __forceinline__ unsigned short f2bf(float f)
{
    unsigned int u = __float_as_uint(f);
    u += 0x7fffu + ((u >> 16) & 1u);
    return (unsigned short)(u >> 16);
}
__device__ __forceinline__ float bf2f(unsigned int bits16)
{
    return __uint_as_float(bits16 << 16);
}

__device__ __forceinline__ float edge_scale(float p)
{
    // clip(log(clip(log(ppmi),1,inf)),1,inf)
    const float lp = fmaxf(__logf(p), 1.0f);
    return fmaxf(__logf(lp), 1.0f);
}

// ---------------------------------------------------------------------------
// Fused: dst-degree histogram (blocks [0,HIST)) + W transpose->bf16
// (blocks [HIST, HIST+WT)). Independent work, disjoint block ranges.
// ---------------------------------------------------------------------------
__global__ __launch_bounds__(256) void k_wt_hist(
    const float* __restrict__ W, unsigned short* __restrict__ Wt_bf,
    const int* __restrict__ dst, int* __restrict__ counts)
{
    const int b = blockIdx.x;
    if (b < HIST_BLOCKS) {
        const int e = b * 256 + threadIdx.x;
        if (e < N_EDGES) atomicAdd(&counts[dst[e]], 1);
    } else {
        const int idx = (b - HIST_BLOCKS) * 256 + threadIdx.x;
        const int n = idx >> 8;          // 0..127
        const int k = idx & 255;         // 0..255
        Wt_bf[n * IN_DIM + k] = f2bf(W[(size_t)k * HD + n]);
    }
}

// ---------------------------------------------------------------------------
// K1: MFMA bf16 GEMM  ft_bf[N x 128] = feat[N x 256] @ W.
// 128x128 block tile, BK=32, 4 waves x (32 rows x 128 cols), 2x8 frags of
// 16x16x32. feat converted fp32->bf16 during LDS staging; W from Wt_bf.
// ---------------------------------------------------------------------------
#define AS 40            // LDS row stride in shorts (80 B = 5*16)
#define CS 136           // C tile row stride in shorts (272 B = 17*16)

__global__ __launch_bounds__(256) void k1_mfma(
    const float* __restrict__ feat, const unsigned short* __restrict__ Wt_bf,
    unsigned short* __restrict__ ft_bf)
{
    __shared__ ushort smem[17408];   // A(5120)+B(5120) shorts / C(17408) shorts
    ushort* A_sh = smem;             // [128][AS]
    ushort* B_sh = smem + 128 * AS;  // [128][AS]

    const int t    = threadIdx.x;
    const int lane = t & 63;
    const int wv   = t >> 6;
    const int r0   = blockIdx.x * 128;

    // staging coords
    const int arow = t >> 3;            // 0..31 (+32p)
    const int akk  = (t & 7) * 4;       // k within chunk
    int rA[4];
#pragma unroll
    for (int p = 0; p < 4; ++p) rA[p] = min(r0 + arow + 32 * p, N_NODES - 1);
    const int bn  = t >> 2;             // 0..63 (+64p)
    const int bk8 = (t & 3) * 8;

    float4 fa[4];
    us8    fb[2];

#define LOADC(kc0)                                                              \
    do {                                                                        \
        _Pragma("unroll")                                                       \
        for (int p = 0; p < 4; ++p)                                             \
            fa[p] = *(const float4*)(feat + (size_t)rA[p] * IN_DIM + (kc0) + akk); \
        _Pragma("unroll")                                                       \
        for (int p = 0; p < 2; ++p)                                             \
            fb[p] = *(const us8*)(Wt_bf + (size_t)(bn + 64 * p) * IN_DIM + (kc0) + bk8); \
    } while (0)

    v4f acc[2][8];
#pragma unroll
    for (int i = 0; i < 2; ++i)
#pragma unroll
        for (int j = 0; j < 8; ++j) acc[i][j] = (v4f)(0.0f);

    const int frow = lane & 15;
    const int fq   = lane >> 4;

    LOADC(0);

    for (int c = 0; c < IN_DIM / 32; ++c) {
        __syncthreads();
        // store staged chunk to LDS (fp32 -> bf16 for A)
#pragma unroll
        for (int p = 0; p < 4; ++p) {
            ushort4 u;
            u.x = f2bf(fa[p].x); u.y = f2bf(fa[p].y);
            u.z = f2bf(fa[p].z); u.w = f2bf(fa[p].w);
            *(ushort4*)(A_sh + (arow + 32 * p) * AS + akk) = u;
        }
#pragma unroll
        for (int p = 0; p < 2; ++p)
            *(us8*)(B_sh + (bn + 64 * p) * AS + bk8) = fb[p];
        __syncthreads();

        if (c + 1 < IN_DIM / 32) LOADC((c + 1) * 32);

        // fragments + MFMA
        v8s a0 = *(const v8s*)(A_sh + (wv * 32 + frow) * AS + fq * 8);
        v8s a1 = *(const v8s*)(A_sh + (wv * 32 + 16 + frow) * AS + fq * 8);
        v8s bfr[8];
#pragma unroll
        for (int nf = 0; nf < 8; ++nf)
            bfr[nf] = *(const v8s*)(B_sh + (nf * 16 + frow) * AS + fq * 8);
#pragma unroll
        for (int nf = 0; nf < 8; ++nf) {
            acc[0][nf] = __builtin_amdgcn_mfma_f32_16x16x32_bf16(
                a0, bfr[nf], acc[0][nf], 0, 0, 0);
            acc[1][nf] = __builtin_amdgcn_mfma_f32_16x16x32_bf16(
                a1, bfr[nf], acc[1][nf], 0, 0, 0);
        }
    }

    // ---- epilogue: per-wave C tile through LDS, coalesced bf16 store ----
    __syncthreads();                       // A/B reads done; reuse LDS as C
    ushort* Cw = smem + wv * (32 * CS);
#pragma unroll
    for (int mf = 0; mf < 2; ++mf)
#pragma unroll
        for (int nf = 0; nf < 8; ++nf)
#pragma unroll
            for (int r = 0; r < 4; ++r)
                Cw[(mf * 16 + fq * 4 + r) * CS + nf * 16 + frow] =
                    f2bf(acc[mf][nf][r]);
    __syncthreads();

    // 16 lanes x us8 = full 128-short row; 4 rows/iter x 8 iters = 32 rows
#pragma unroll
    for (int p = 0; p < 8; ++p) {
        const int row_l = (lane >> 4) + 4 * p;
        const int colv  = (lane & 15) * 8;
        const us8 val = *(const us8*)(Cw + row_l * CS + colv);
        const int grow = r0 + wv * 32 + row_l;
        if (grow < N_NODES)
            *(us8*)(ft_bf + (size_t)grow * HD + colv) = val;
    }
}

// ---------------------------------------------------------------------------
// Fused: scan_local (blocks [0,SCAN)) + k1b per-(node,head) scalars
// (blocks [SCAN, SCAN+K1B)). scan_local depends on hist; k1b depends on k1.
// ---------------------------------------------------------------------------
__global__ __launch_bounds__(256) void k_k1b_scanlocal(
    const int* __restrict__ counts, int* __restrict__ local,
    int* __restrict__ bsums,
    const unsigned short* __restrict__ ft_bf,
    const float* __restrict__ mu_src, const float* __restrict__ mu_dst,
    const float* __restrict__ lam_src,
    const float* __restrict__ eps_src, const float* __restrict__ eps_dst,
    float* __restrict__ z_src_ws, float* __restrict__ z_dst_ws,
    float* __restrict__ mu_out, float* __restrict__ lam_out)
{
    __shared__ int sh[256];
    const int b = blockIdx.x;
    const int t = threadIdx.x;

    if (b < SCAN_BLOCKS) {
        const int i = b * 256 + t;
        const int v = (i < N_NODES) ? counts[i] : 0;
        sh[t] = v;
        __syncthreads();
#pragma unroll
        for (int off = 1; off < 256; off <<= 1) {
            int x = (t >= off) ? sh[t - off] : 0;
            __syncthreads();
            sh[t] += x;
            __syncthreads();
        }
        if (i < N_NODES) local[i] = sh[t] - v;
        if (t == 255) bsums[b] = sh[255];
        return;
    }

    // ---- k1b part ----
    const int g = (b - SCAN_BLOCKS) * 256 + t;       // (row, head) flat
    if (g >= N_NODES * NH) return;
    const int row = g >> 2;
    const int h   = g & 3;

    const unsigned short* fr = ft_bf + (size_t)row * HD + h * 32;
    const float* ms = mu_src + h * 32;
    const float* md = mu_dst + h * 32;
    const float* ls = lam_src + h * 32;

    float pm = 0.0f, pd = 0.0f, pl = 0.0f;
#pragma unroll
    for (int v = 0; v < 4; ++v) {
        const us8 u = *(const us8*)(fr + v * 8);
#pragma unroll
        for (int j = 0; j < 8; ++j) {
            const float f = bf2f(u[j]);
            const int   i = v * 8 + j;
            pm = fmaf(f, ms[i], pm);
            pd = fmaf(f, md[i], pd);
            pl = fmaf(f, ls[i], pl);
        }
    }
    const float sdev = expf(0.5f * pl);
    z_src_ws[g] = eps_src[g] * sdev + pm;
    z_dst_ws[g] = eps_dst[g] * sdev + pd;
    mu_out[g]   = pm + pd;
    lam_out[g]  = 2.0f * pl;     // lam_d == lam_s in reference
}

// ---------------------------------------------------------------------------
__global__ __launch_bounds__(256) void k_scan_bsums(
    const int* __restrict__ bsums, int* __restrict__ bscan)
{
    __shared__ int sh[256];
    const int t = threadIdx.x;
    const int v = (t < SCAN_BLOCKS) ? bsums[t] : 0;
    sh[t] = v;
    __syncthreads();
#pragma unroll
    for (int off = 1; off < 256; off <<= 1) {
        int x = (t >= off) ? sh[t - off] : 0;
        __syncthreads();
        sh[t] += x;
        __syncthreads();
    }
    if (t < SCAN_BLOCKS) bscan[t] = sh[t] - v;
}

__global__ __launch_bounds__(256) void k_scan_add(
    const int* __restrict__ local, const int* __restrict__ bscan,
    int* __restrict__ offsets, int* __restrict__ cursor)
{
    const int i = blockIdx.x * 256 + threadIdx.x;
    if (i >= N_NODES) return;
    const int o = local[i] + bscan[blockIdx.x];
    offsets[i] = o;
    cursor[i]  = o;
}

// ---------------------------------------------------------------------------
// Scatter edges into dst-sorted order: 8B record {src, scale_fp32}.
// No z reads, no exp — shortest possible chain before the random write.
// ---------------------------------------------------------------------------
__global__ __launch_bounds__(256) void k_scatter(
    const int* __restrict__ src, const int* __restrict__ dst,
    const float* __restrict__ ppmi,
    int* __restrict__ cursor, int2* __restrict__ rec_sorted)
{
    const int e = blockIdx.x * 256 + threadIdx.x;
    if (e >= N_EDGES) return;
    const int s  = src[e];
    const int d0 = dst[e];
    const int j  = atomicAdd(&cursor[d0], 1);
    rec_sorted[j] = make_int2(s, __float_as_int(edge_scale(ppmi[e])));
}

// ---------------------------------------------------------------------------
// K3: CSR segmented reduction, unrolled x4 with independent gather chains.
// Recomputes w = exp(lrelu(z_src[s]+z_dst[node])*scale) per edge (fp32).
// ---------------------------------------------------------------------------
__device__ __forceinline__ float edge_w1(float zs, float zd, float sc)
{
    float v = zs + zd;
    v = (v >= 0.0f) ? v : NEG_SLOPE * v;
    return __expf(v * sc);
}

__global__ __launch_bounds__(64) void k3_csr(
    const int* __restrict__ offsets, const int* __restrict__ counts,
    const int2* __restrict__ rec_sorted,
    const float* __restrict__ z_src_ws, const float* __restrict__ z_dst_ws,
    const unsigned int* __restrict__ ft_u32, float2* __restrict__ rst2)
{
    const int node = blockIdx.x;
    const int lane = threadIdx.x;
    const int h    = lane >> 4;                 // head = (2*lane)/32
    const int start = offsets[node];
    const int deg   = counts[node];
    const float zd  = z_dst_ws[node * NH + h];

    float ax = 0.0f, ay = 0.0f, wsum = 0.0f;

    int i = 0;
    for (; i + 4 <= deg; i += 4) {
        const int2 r0 = rec_sorted[start + i];
        const int2 r1 = rec_sorted[start + i + 1];
        const int2 r2 = rec_sorted[start + i + 2];
        const int2 r3 = rec_sorted[start + i + 3];
        const float z0 = z_src_ws[r0.x * NH + h];
        const float z1 = z_src_ws[r1.x * NH + h];
        const float z2 = z_src_ws[r2.x * NH + h];
        const float z3 = z_src_ws[r3.x * NH + h];
        const unsigned f0 = ft_u32[(size_t)r0.x * (HD / 2) + lane];
        const unsigned f1 = ft_u32[(size_t)r1.x * (HD / 2) + lane];
        const unsigned f2 = ft_u32[(size_t)r2.x * (HD / 2) + lane];
        const unsigned f3 = ft_u32[(size_t)r3.x * (HD / 2) + lane];
        const float w0 = edge_w1(z0, zd, __int_as_float(r0.y));
        const float w1 = edge_w1(z1, zd, __int_as_float(r1.y));
        const float w2 = edge_w1(z2, zd, __int_as_float(r2.y));
        const float w3 = edge_w1(z3, zd, __int_as_float(r3.y));
        ax = fmaf(bf2f(f0 & 0xffffu), w0, ax);
        ay = fmaf(bf2f(f0 >> 16),     w0, ay);
        ax = fmaf(bf2f(f1 & 0xffffu), w1, ax);
        ay = fmaf(bf2f(f1 >> 16),     w1, ay);
        ax = fmaf(bf2f(f2 & 0xffffu), w2, ax);
        ay = fmaf(bf2f(f2 >> 16),     w2, ay);
        ax = fmaf(bf2f(f3 & 0xffffu), w3, ax);
        ay = fmaf(bf2f(f3 >> 16),     w3, ay);
        wsum += (w0 + w1) + (w2 + w3);
    }
    for (; i < deg; ++i) {
        const int2 r0 = rec_sorted[start + i];
        const float z0 = z_src_ws[r0.x * NH + h];
        const unsigned f0 = ft_u32[(size_t)r0.x * (HD / 2) + lane];
        const float w0 = edge_w1(z0, zd, __int_as_float(r0.y));
        ax = fmaf(bf2f(f0 & 0xffffu), w0, ax);
        ay = fmaf(bf2f(f0 >> 16),     w0, ay);
        wsum += w0;
    }

    const float inv = (wsum > 0.0f) ? 1.0f / wsum : 0.0f;
    rst2[(size_t)node * (HD / 2) + lane] = make_float2(ax * inv, ay * inv);
}

// ---------------------------------------------------------------------------
extern "C" void kernel_launch(void* const* d_in, const int* in_sizes, int n_in,
                              void* d_out, int out_size, void* d_ws, size_t ws_size,
                              hipStream_t stream)
{
    const float* feat    = (const float*)d_in[0];
    const int*   src     = (const int*)  d_in[1];
    const int*   dst     = (const int*)  d_in[2];
    const float* ppmi    = (const float*)d_in[3];
    const float* eps_src = (const float*)d_in[4];
    const float* eps_dst = (const float*)d_in[5];
    const float* W       = (const float*)d_in[6];
    const float* mu_src  = (const float*)d_in[7];
    const float* mu_dst  = (const float*)d_in[8];
    const float* lam_src = (const float*)d_in[9];
    // d_in[10] = lam_dst: unused by the reference math

    float* out     = (float*)d_out;
    float* rst     = out;                                 // N*HD
    float* mu_out  = out + (size_t)N_NODES * HD;          // N*NH
    float* lam_out = mu_out + (size_t)N_NODES * NH;       // N*NH

    // workspace layout (16B-aligned first)
    char* wsb = (char*)d_ws;
    int2*           rec_s  = (int2*)wsb;                                   // E*8B
    unsigned short* ft_bf  = (unsigned short*)(wsb + (size_t)N_EDGES * 8); // N*HD*2
    unsigned short* Wt_bf  = ft_bf + (size_t)N_NODES * HD;                 // 128*256
    float*          zs_ws  = (float*)(Wt_bf + (size_t)HD * IN_DIM);
    float*          zd_ws  = zs_ws + (size_t)N_NODES * NH;
    int*            counts = (int*)(zd_ws + (size_t)N_NODES * NH);
    int*            local  = counts + N_NODES;
    int*            offsets= local + N_NODES;
    int*            cursor = offsets + N_NODES;
    int*            bsums  = cursor + N_NODES;
    int*            bscan  = bsums + 256;

    hipMemsetAsync(counts, 0, N_NODES * sizeof(int), stream);

    k_wt_hist<<<HIST_BLOCKS + WT_BLOCKS, 256, 0, stream>>>(
        W, Wt_bf, dst, counts);

    k1_mfma<<<(N_NODES + 127) / 128, 256, 0, stream>>>(feat, Wt_bf, ft_bf);

    k_k1b_scanlocal<<<SCAN_BLOCKS + K1B_BLOCKS, 256, 0, stream>>>(
        counts, local, bsums,
        ft_bf, mu_src, mu_dst, lam_src, eps_src, eps_dst,
        zs_ws, zd_ws, mu_out, lam_out);

    k_scan_bsums<<<1, 256, 0, stream>>>(bsums, bscan);
    k_scan_add<<<SCAN_BLOCKS, 256, 0, stream>>>(local, bscan, offsets, cursor);

    k_scatter<<<HIST_BLOCKS, 256, 0, stream>>>(src, dst, ppmi, cursor, rec_s);

    k3_csr<<<N_NODES, 64, 0, stream>>>(
        offsets, counts, rec_s, zs_ws, zd_ws,
        (const unsigned int*)ft_bf, (float2*)rst);
}

// Round 8
// 240.079 us; speedup vs baseline: 7.8668x; 1.0745x over previous
//
#include <hip/hip_runtime.h>

#define N_NODES 50000
#define N_EDGES 800000
#define IN_DIM  256
#define NH      4
#define HD      128   // NH * 32
#define NEG_SLOPE 0.2f
#define SCAN_BLOCKS ((N_NODES + 255) / 256)    // 196
#define HIST_BLOCKS ((N_EDGES + 255) / 256)    // 3125
#define WT_BLOCKS   ((HD * IN_DIM) / 256)      // 128
#define K1B_BLOCKS  ((N_NODES * NH + 255) / 256) // 782

typedef short          v8s __attribute__((ext_vector_type(8)));
typedef float          v4f __attribute__((ext_vector_type(4)));
typedef unsigned short us8 __attribute__((ext_vector_type(8)));
typedef int            v4i __attribute__((ext_vector_type(4)));

// RNE float -> bf16 bits
__device__ __forceinline__ unsigned short f2bf(float f)
{
    unsigned int u = __float_as_uint(f);
    u += 0x7fffu + ((u >> 16) & 1u);
    return (unsigned short)(u >> 16);
}
__device__ __forceinline__ float bf2f(unsigned int bits16)
{
    return __uint_as_float(bits16 << 16);
}

__device__ __forceinline__ float edge_scale(float p)
{
    // clip(log(clip(log(ppmi),1,inf)),1,inf)
    const float lp = fmaxf(__logf(p), 1.0f);
    return fmaxf(__logf(lp), 1.0f);
}

// ---------------------------------------------------------------------------
// Fused: dst-degree histogram + per-edge rank capture (blocks [0,HIST)) and
// W transpose->bf16 (blocks [HIST, HIST+WT)).
// ---------------------------------------------------------------------------
__global__ __launch_bounds__(256) void k_wt_hist(
    const float* __restrict__ W, unsigned short* __restrict__ Wt_bf,
    const int* __restrict__ dst, int* __restrict__ counts,
    int* __restrict__ rank)
{
    const int b = blockIdx.x;
    if (b < HIST_BLOCKS) {
        const int e = b * 256 + threadIdx.x;
        if (e < N_EDGES) rank[e] = atomicAdd(&counts[dst[e]], 1);
    } else {
        const int idx = (b - HIST_BLOCKS) * 256 + threadIdx.x;
        const int n = idx >> 8;          // 0..127
        const int k = idx & 255;         // 0..255
        Wt_bf[n * IN_DIM + k] = f2bf(W[(size_t)k * HD + n]);
    }
}

// ---------------------------------------------------------------------------
// K1: MFMA bf16 GEMM  ft_bf[N x 128] = feat[N x 256] @ W.
// ---------------------------------------------------------------------------
#define AS 40            // LDS row stride in shorts (80 B = 5*16)
#define CS 136           // C tile row stride in shorts (272 B = 17*16)

__global__ __launch_bounds__(256) void k1_mfma(
    const float* __restrict__ feat, const unsigned short* __restrict__ Wt_bf,
    unsigned short* __restrict__ ft_bf)
{
    __shared__ ushort smem[17408];   // A(5120)+B(5120) shorts / C(17408) shorts
    ushort* A_sh = smem;             // [128][AS]
    ushort* B_sh = smem + 128 * AS;  // [128][AS]

    const int t    = threadIdx.x;
    const int lane = t & 63;
    const int wv   = t >> 6;
    const int r0   = blockIdx.x * 128;

    // staging coords
    const int arow = t >> 3;            // 0..31 (+32p)
    const int akk  = (t & 7) * 4;       // k within chunk
    int rA[4];
#pragma unroll
    for (int p = 0; p < 4; ++p) rA[p] = min(r0 + arow + 32 * p, N_NODES - 1);
    const int bn  = t >> 2;             // 0..63 (+64p)
    const int bk8 = (t & 3) * 8;

    float4 fa[4];
    us8    fb[2];

#define LOADC(kc0)                                                              \
    do {                                                                        \
        _Pragma("unroll")                                                       \
        for (int p = 0; p < 4; ++p)                                             \
            fa[p] = *(const float4*)(feat + (size_t)rA[p] * IN_DIM + (kc0) + akk); \
        _Pragma("unroll")                                                       \
        for (int p = 0; p < 2; ++p)                                             \
            fb[p] = *(const us8*)(Wt_bf + (size_t)(bn + 64 * p) * IN_DIM + (kc0) + bk8); \
    } while (0)

    v4f acc[2][8];
#pragma unroll
    for (int i = 0; i < 2; ++i)
#pragma unroll
        for (int j = 0; j < 8; ++j) acc[i][j] = (v4f)(0.0f);

    const int frow = lane & 15;
    const int fq   = lane >> 4;

    LOADC(0);

    for (int c = 0; c < IN_DIM / 32; ++c) {
        __syncthreads();
        // store staged chunk to LDS (fp32 -> bf16 for A)
#pragma unroll
        for (int p = 0; p < 4; ++p) {
            ushort4 u;
            u.x = f2bf(fa[p].x); u.y = f2bf(fa[p].y);
            u.z = f2bf(fa[p].z); u.w = f2bf(fa[p].w);
            *(ushort4*)(A_sh + (arow + 32 * p) * AS + akk) = u;
        }
#pragma unroll
        for (int p = 0; p < 2; ++p)
            *(us8*)(B_sh + (bn + 64 * p) * AS + bk8) = fb[p];
        __syncthreads();

        if (c + 1 < IN_DIM / 32) LOADC((c + 1) * 32);

        // fragments + MFMA
        v8s a0 = *(const v8s*)(A_sh + (wv * 32 + frow) * AS + fq * 8);
        v8s a1 = *(const v8s*)(A_sh + (wv * 32 + 16 + frow) * AS + fq * 8);
        v8s bfr[8];
#pragma unroll
        for (int nf = 0; nf < 8; ++nf)
            bfr[nf] = *(const v8s*)(B_sh + (nf * 16 + frow) * AS + fq * 8);
#pragma unroll
        for (int nf = 0; nf < 8; ++nf) {
            acc[0][nf] = __builtin_amdgcn_mfma_f32_16x16x32_bf16(
                a0, bfr[nf], acc[0][nf], 0, 0, 0);
            acc[1][nf] = __builtin_amdgcn_mfma_f32_16x16x32_bf16(
                a1, bfr[nf], acc[1][nf], 0, 0, 0);
        }
    }

    // ---- epilogue: per-wave C tile through LDS, coalesced bf16 store ----
    __syncthreads();                       // A/B reads done; reuse LDS as C
    ushort* Cw = smem + wv * (32 * CS);
#pragma unroll
    for (int mf = 0; mf < 2; ++mf)
#pragma unroll
        for (int nf = 0; nf < 8; ++nf)
#pragma unroll
            for (int r = 0; r < 4; ++r)
                Cw[(mf * 16 + fq * 4 + r) * CS + nf * 16 + frow] =
                    f2bf(acc[mf][nf][r]);
    __syncthreads();

    // 16 lanes x us8 = full 128-short row; 4 rows/iter x 8 iters = 32 rows
#pragma unroll
    for (int p = 0; p < 8; ++p) {
        const int row_l = (lane >> 4) + 4 * p;
        const int colv  = (lane & 15) * 8;
        const us8 val = *(const us8*)(Cw + row_l * CS + colv);
        const int grow = r0 + wv * 32 + row_l;
        if (grow < N_NODES)
            *(us8*)(ft_bf + (size_t)grow * HD + colv) = val;
    }
}

// ---------------------------------------------------------------------------
// Fused: scan_local (blocks [0,SCAN)) + k1b per-(node,head) scalars
// (blocks [SCAN, SCAN+K1B)).
// ---------------------------------------------------------------------------
__global__ __launch_bounds__(256) void k_k1b_scanlocal(
    const int* __restrict__ counts, int* __restrict__ local,
    int* __restrict__ bsums,
    const unsigned short* __restrict__ ft_bf,
    const float* __restrict__ mu_src, const float* __restrict__ mu_dst,
    const float* __restrict__ lam_src,
    const float* __restrict__ eps_src, const float* __restrict__ eps_dst,
    float* __restrict__ z_src_ws, float* __restrict__ z_dst_ws,
    float* __restrict__ mu_out, float* __restrict__ lam_out)
{
    __shared__ int sh[256];
    const int b = blockIdx.x;
    const int t = threadIdx.x;

    if (b < SCAN_BLOCKS) {
        const int i = b * 256 + t;
        const int v = (i < N_NODES) ? counts[i] : 0;
        sh[t] = v;
        __syncthreads();
#pragma unroll
        for (int off = 1; off < 256; off <<= 1) {
            int x = (t >= off) ? sh[t - off] : 0;
            __syncthreads();
            sh[t] += x;
            __syncthreads();
        }
        if (i < N_NODES) local[i] = sh[t] - v;
        if (t == 255) bsums[b] = sh[255];
        return;
    }

    // ---- k1b part ----
    const int g = (b - SCAN_BLOCKS) * 256 + t;       // (row, head) flat
    if (g >= N_NODES * NH) return;
    const int row = g >> 2;
    const int h   = g & 3;

    const unsigned short* fr = ft_bf + (size_t)row * HD + h * 32;
    const float* ms = mu_src + h * 32;
    const float* md = mu_dst + h * 32;
    const float* ls = lam_src + h * 32;

    float pm = 0.0f, pd = 0.0f, pl = 0.0f;
#pragma unroll
    for (int v = 0; v < 4; ++v) {
        const us8 u = *(const us8*)(fr + v * 8);
#pragma unroll
        for (int j = 0; j < 8; ++j) {
            const float f = bf2f(u[j]);
            const int   i = v * 8 + j;
            pm = fmaf(f, ms[i], pm);
            pd = fmaf(f, md[i], pd);
            pl = fmaf(f, ls[i], pl);
        }
    }
    const float sdev = expf(0.5f * pl);
    z_src_ws[g] = eps_src[g] * sdev + pm;
    z_dst_ws[g] = eps_dst[g] * sdev + pd;
    mu_out[g]   = pm + pd;
    lam_out[g]  = 2.0f * pl;     // lam_d == lam_s in reference
}

// ---------------------------------------------------------------------------
__global__ __launch_bounds__(256) void k_scan_bsums(
    const int* __restrict__ bsums, int* __restrict__ bscan)
{
    __shared__ int sh[256];
    const int t = threadIdx.x;
    const int v = (t < SCAN_BLOCKS) ? bsums[t] : 0;
    sh[t] = v;
    __syncthreads();
#pragma unroll
    for (int off = 1; off < 256; off <<= 1) {
        int x = (t >= off) ? sh[t - off] : 0;
        __syncthreads();
        sh[t] += x;
        __syncthreads();
    }
    if (t < SCAN_BLOCKS) bscan[t] = sh[t] - v;
}

__global__ __launch_bounds__(256) void k_scan_add(
    const int* __restrict__ local, const int* __restrict__ bscan,
    int* __restrict__ offsets)
{
    const int i = blockIdx.x * 256 + threadIdx.x;
    if (i >= N_NODES) return;
    offsets[i] = local[i] + bscan[blockIdx.x];
}

// ---------------------------------------------------------------------------
// Scatter edges into dst-sorted order. Atomic-free: j = offsets[dst]+rank.
// 16B padded record (avoids 8-way inter-XCD line sharing), nontemporal
// store (no L2 allocate -> no line ping-pong).
// ---------------------------------------------------------------------------
__global__ __launch_bounds__(256) void k_scatter(
    const int* __restrict__ src, const int* __restrict__ dst,
    const float* __restrict__ ppmi, const int* __restrict__ rank,
    const int* __restrict__ offsets, v4i* __restrict__ rec_sorted)
{
    const int e = blockIdx.x * 256 + threadIdx.x;
    if (e >= N_EDGES) return;
    const int d0 = dst[e];
    const int j  = offsets[d0] + rank[e];
    v4i rec;
    rec.x = src[e];
    rec.y = __float_as_int(edge_scale(ppmi[e]));
    rec.z = 0;
    rec.w = 0;
    __builtin_nontemporal_store(rec, rec_sorted + j);
}

// ---------------------------------------------------------------------------
// K3: CSR segmented reduction, unrolled x4 with independent gather chains.
// Recomputes w = exp(lrelu(z_src[s]+z_dst[node])*scale) per edge (fp32).
// ---------------------------------------------------------------------------
__device__ __forceinline__ float edge_w1(float zs, float zd, float sc)
{
    float v = zs + zd;
    v = (v >= 0.0f) ? v : NEG_SLOPE * v;
    return __expf(v * sc);
}

__global__ __launch_bounds__(64) void k3_csr(
    const int* __restrict__ offsets, const int* __restrict__ counts,
    const v4i* __restrict__ rec_sorted,
    const float* __restrict__ z_src_ws, const float* __restrict__ z_dst_ws,
    const unsigned int* __restrict__ ft_u32, float2* __restrict__ rst2)
{
    const int node = blockIdx.x;
    const int lane = threadIdx.x;
    const int h    = lane >> 4;                 // head = (2*lane)/32
    const int start = offsets[node];
    const int deg   = counts[node];
    const float zd  = z_dst_ws[node * NH + h];

    float ax = 0.0f, ay = 0.0f, wsum = 0.0f;

    int i = 0;
    for (; i + 4 <= deg; i += 4) {
        const v4i r0 = __builtin_nontemporal_load(rec_sorted + start + i);
        const v4i r1 = __builtin_nontemporal_load(rec_sorted + start + i + 1);
        const v4i r2 = __builtin_nontemporal_load(rec_sorted + start + i + 2);
        const v4i r3 = __builtin_nontemporal_load(rec_sorted + start + i + 3);
        const float z0 = z_src_ws[r0.x * NH + h];
        const float z1 = z_src_ws[r1.x * NH + h];
        const float z2 = z_src_ws[r2.x * NH + h];
        const float z3 = z_src_ws[r3.x * NH + h];
        const unsigned f0 = ft_u32[(size_t)r0.x * (HD / 2) + lane];
        const unsigned f1 = ft_u32[(size_t)r1.x * (HD / 2) + lane];
        const unsigned f2 = ft_u32[(size_t)r2.x * (HD / 2) + lane];
        const unsigned f3 = ft_u32[(size_t)r3.x * (HD / 2) + lane];
        const float w0 = edge_w1(z0, zd, __int_as_float(r0.y));
        const float w1 = edge_w1(z1, zd, __int_as_float(r1.y));
        const float w2 = edge_w1(z2, zd, __int_as_float(r2.y));
        const float w3 = edge_w1(z3, zd, __int_as_float(r3.y));
        ax = fmaf(bf2f(f0 & 0xffffu), w0, ax);
        ay = fmaf(bf2f(f0 >> 16),     w0, ay);
        ax = fmaf(bf2f(f1 & 0xffffu), w1, ax);
        ay = fmaf(bf2f(f1 >> 16),     w1, ay);
        ax = fmaf(bf2f(f2 & 0xffffu), w2, ax);
        ay = fmaf(bf2f(f2 >> 16),     w2, ay);
        ax = fmaf(bf2f(f3 & 0xffffu), w3, ax);
        ay = fmaf(bf2f(f3 >> 16),     w3, ay);
        wsum += (w0 + w1) + (w2 + w3);
    }
    for (; i < deg; ++i) {
        const v4i r0 = __builtin_nontemporal_load(rec_sorted + start + i);
        const float z0 = z_src_ws[r0.x * NH + h];
        const unsigned f0 = ft_u32[(size_t)r0.x * (HD / 2) + lane];
        const float w0 = edge_w1(z0, zd, __int_as_float(r0.y));
        ax = fmaf(bf2f(f0 & 0xffffu), w0, ax);
        ay = fmaf(bf2f(f0 >> 16),     w0, ay);
        wsum += w0;
    }

    const float inv = (wsum > 0.0f) ? 1.0f / wsum : 0.0f;
    rst2[(size_t)node * (HD / 2) + lane] = make_float2(ax * inv, ay * inv);
}

// ---------------------------------------------------------------------------
extern "C" void kernel_launch(void* const* d_in, const int* in_sizes, int n_in,
                              void* d_out, int out_size, void* d_ws, size_t ws_size,
                              hipStream_t stream)
{
    const float* feat    = (const float*)d_in[0];
    const int*   src     = (const int*)  d_in[1];
    const int*   dst     = (const int*)  d_in[2];
    const float* ppmi    = (const float*)d_in[3];
    const float* eps_src = (const float*)d_in[4];
    const float* eps_dst = (const float*)d_in[5];
    const float* W       = (const float*)d_in[6];
    const float* mu_src  = (const float*)d_in[7];
    const float* mu_dst  = (const float*)d_in[8];
    const float* lam_src = (const float*)d_in[9];
    // d_in[10] = lam_dst: unused by the reference math

    float* out     = (float*)d_out;
    float* rst     = out;                                 // N*HD
    float* mu_out  = out + (size_t)N_NODES * HD;          // N*NH
    float* lam_out = mu_out + (size_t)N_NODES * NH;       // N*NH

    // workspace layout (16B-aligned first)
    char* wsb = (char*)d_ws;
    v4i*            rec_s  = (v4i*)wsb;                                    // E*16B
    unsigned short* ft_bf  = (unsigned short*)(wsb + (size_t)N_EDGES * 16);// N*HD*2
    unsigned short* Wt_bf  = ft_bf + (size_t)N_NODES * HD;                 // 128*256
    float*          zs_ws  = (float*)(Wt_bf + (size_t)HD * IN_DIM);
    float*          zd_ws  = zs_ws + (size_t)N_NODES * NH;
    int*            counts = (int*)(zd_ws + (size_t)N_NODES * NH);
    int*            local  = counts + N_NODES;
    int*            offsets= local + N_NODES;
    int*            bsums  = offsets + N_NODES;
    int*            bscan  = bsums + 256;
    int*            rank   = bscan + 256;                                  // E

    hipMemsetAsync(counts, 0, N_NODES * sizeof(int), stream);

    k_wt_hist<<<HIST_BLOCKS + WT_BLOCKS, 256, 0, stream>>>(
        W, Wt_bf, dst, counts, rank);

    k1_mfma<<<(N_NODES + 127) / 128, 256, 0, stream>>>(feat, Wt_bf, ft_bf);

    k_k1b_scanlocal<<<SCAN_BLOCKS + K1B_BLOCKS, 256, 0, stream>>>(
        counts, local, bsums,
        ft_bf, mu_src, mu_dst, lam_src, eps_src, eps_dst,
        zs_ws, zd_ws, mu_out, lam_out);

    k_scan_bsums<<<1, 256, 0, stream>>>(bsums, bscan);
    k_scan_add<<<SCAN_BLOCKS, 256, 0, stream>>>(local, bscan, offsets);

    k_scatter<<<HIST_BLOCKS, 256, 0, stream>>>(
        src, dst, ppmi, rank, offsets, rec_s);

    k3_csr<<<N_NODES, 64, 0, stream>>>(
        offsets, counts, rec_s, zs_ws, zd_ws,
        (const unsigned int*)ft_bf, (float2*)rst);
}

// Round 9
// 239.241 us; speedup vs baseline: 7.8943x; 1.0035x over previous
//
#include <hip/hip_runtime.h>

#define N_NODES 50000
#define N_EDGES 800000
#define IN_DIM  256
#define NH      4
#define HD      128   // NH * 32
#define NEG_SLOPE 0.2f
#define SCAN_BLOCKS ((N_NODES + 255) / 256)    // 196
#define HIST_BLOCKS ((N_EDGES + 255) / 256)    // 3125
#define WT_BLOCKS   ((HD * IN_DIM) / 256)      // 128
#define K1B_BLOCKS  ((N_NODES * NH + 255) / 256) // 782

typedef short          v8s __attribute__((ext_vector_type(8)));
typedef float          v4f __attribute__((ext_vector_type(4)));
typedef unsigned short us8 __attribute__((ext_vector_type(8)));
typedef int            v4i __attribute__((ext_vector_type(4)));

// RNE float -> bf16 bits
__device__ __forceinline__ unsigned short f2bf(float f)
{
    unsigned int u = __float_as_uint(f);
    u += 0x7fffu + ((u >> 16) & 1u);
    return (unsigned short)(u >> 16);
}
__device__ __forceinline__ float bf2f(unsigned int bits16)
{
    return __uint_as_float(bits16 << 16);
}

__device__ __forceinline__ float edge_scale(float p)
{
    // clip(log(clip(log(ppmi),1,inf)),1,inf)
    const float lp = fmaxf(__logf(p), 1.0f);
    return fmaxf(__logf(lp), 1.0f);
}

// ---------------------------------------------------------------------------
// Fused: dst-degree histogram + per-edge rank capture (blocks [0,HIST)) and
// W transpose->bf16 (blocks [HIST, HIST+WT)).
// ---------------------------------------------------------------------------
__global__ __launch_bounds__(256) void k_wt_hist(
    const float* __restrict__ W, unsigned short* __restrict__ Wt_bf,
    const int* __restrict__ dst, int* __restrict__ counts,
    int* __restrict__ rank)
{
    const int b = blockIdx.x;
    if (b < HIST_BLOCKS) {
        const int e = b * 256 + threadIdx.x;
        if (e < N_EDGES) rank[e] = atomicAdd(&counts[dst[e]], 1);
    } else {
        const int idx = (b - HIST_BLOCKS) * 256 + threadIdx.x;
        const int n = idx >> 8;          // 0..127
        const int k = idx & 255;         // 0..255
        Wt_bf[n * IN_DIM + k] = f2bf(W[(size_t)k * HD + n]);
    }
}

// ---------------------------------------------------------------------------
// K1: MFMA bf16 GEMM  ft_bf[N x 128] = feat[N x 256] @ W.
// ---------------------------------------------------------------------------
#define AS 40            // LDS row stride in shorts (80 B = 5*16)
#define CS 136           // C tile row stride in shorts (272 B = 17*16)

__global__ __launch_bounds__(256) void k1_mfma(
    const float* __restrict__ feat, const unsigned short* __restrict__ Wt_bf,
    unsigned short* __restrict__ ft_bf)
{
    __shared__ ushort smem[17408];   // A(5120)+B(5120) shorts / C(17408) shorts
    ushort* A_sh = smem;             // [128][AS]
    ushort* B_sh = smem + 128 * AS;  // [128][AS]

    const int t    = threadIdx.x;
    const int lane = t & 63;
    const int wv   = t >> 6;
    const int r0   = blockIdx.x * 128;

    // staging coords
    const int arow = t >> 3;            // 0..31 (+32p)
    const int akk  = (t & 7) * 4;       // k within chunk
    int rA[4];
#pragma unroll
    for (int p = 0; p < 4; ++p) rA[p] = min(r0 + arow + 32 * p, N_NODES - 1);
    const int bn  = t >> 2;             // 0..63 (+64p)
    const int bk8 = (t & 3) * 8;

    float4 fa[4];
    us8    fb[2];

#define LOADC(kc0)                                                              \
    do {                                                                        \
        _Pragma("unroll")                                                       \
        for (int p = 0; p < 4; ++p)                                             \
            fa[p] = *(const float4*)(feat + (size_t)rA[p] * IN_DIM + (kc0) + akk); \
        _Pragma("unroll")                                                       \
        for (int p = 0; p < 2; ++p)                                             \
            fb[p] = *(const us8*)(Wt_bf + (size_t)(bn + 64 * p) * IN_DIM + (kc0) + bk8); \
    } while (0)

    v4f acc[2][8];
#pragma unroll
    for (int i = 0; i < 2; ++i)
#pragma unroll
        for (int j = 0; j < 8; ++j) acc[i][j] = (v4f)(0.0f);

    const int frow = lane & 15;
    const int fq   = lane >> 4;

    LOADC(0);

    for (int c = 0; c < IN_DIM / 32; ++c) {
        __syncthreads();
        // store staged chunk to LDS (fp32 -> bf16 for A)
#pragma unroll
        for (int p = 0; p < 4; ++p) {
            ushort4 u;
            u.x = f2bf(fa[p].x); u.y = f2bf(fa[p].y);
            u.z = f2bf(fa[p].z); u.w = f2bf(fa[p].w);
            *(ushort4*)(A_sh + (arow + 32 * p) * AS + akk) = u;
        }
#pragma unroll
        for (int p = 0; p < 2; ++p)
            *(us8*)(B_sh + (bn + 64 * p) * AS + bk8) = fb[p];
        __syncthreads();

        if (c + 1 < IN_DIM / 32) LOADC((c + 1) * 32);

        // fragments + MFMA
        v8s a0 = *(const v8s*)(A_sh + (wv * 32 + frow) * AS + fq * 8);
        v8s a1 = *(const v8s*)(A_sh + (wv * 32 + 16 + frow) * AS + fq * 8);
        v8s bfr[8];
#pragma unroll
        for (int nf = 0; nf < 8; ++nf)
            bfr[nf] = *(const v8s*)(B_sh + (nf * 16 + frow) * AS + fq * 8);
#pragma unroll
        for (int nf = 0; nf < 8; ++nf) {
            acc[0][nf] = __builtin_amdgcn_mfma_f32_16x16x32_bf16(
                a0, bfr[nf], acc[0][nf], 0, 0, 0);
            acc[1][nf] = __builtin_amdgcn_mfma_f32_16x16x32_bf16(
                a1, bfr[nf], acc[1][nf], 0, 0, 0);
        }
    }

    // ---- epilogue: per-wave C tile through LDS, coalesced bf16 store ----
    __syncthreads();                       // A/B reads done; reuse LDS as C
    ushort* Cw = smem + wv * (32 * CS);
#pragma unroll
    for (int mf = 0; mf < 2; ++mf)
#pragma unroll
        for (int nf = 0; nf < 8; ++nf)
#pragma unroll
            for (int r = 0; r < 4; ++r)
                Cw[(mf * 16 + fq * 4 + r) * CS + nf * 16 + frow] =
                    f2bf(acc[mf][nf][r]);
    __syncthreads();

    // 16 lanes x us8 = full 128-short row; 4 rows/iter x 8 iters = 32 rows
#pragma unroll
    for (int p = 0; p < 8; ++p) {
        const int row_l = (lane >> 4) + 4 * p;
        const int colv  = (lane & 15) * 8;
        const us8 val = *(const us8*)(Cw + row_l * CS + colv);
        const int grow = r0 + wv * 32 + row_l;
        if (grow < N_NODES)
            *(us8*)(ft_bf + (size_t)grow * HD + colv) = val;
    }
}

// ---------------------------------------------------------------------------
// Fused: scan_local (blocks [0,SCAN)) + k1b per-(node,head) scalars
// (blocks [SCAN, SCAN+K1B)).
// ---------------------------------------------------------------------------
__global__ __launch_bounds__(256) void k_k1b_scanlocal(
    const int* __restrict__ counts, int* __restrict__ local,
    int* __restrict__ bsums,
    const unsigned short* __restrict__ ft_bf,
    const float* __restrict__ mu_src, const float* __restrict__ mu_dst,
    const float* __restrict__ lam_src,
    const float* __restrict__ eps_src, const float* __restrict__ eps_dst,
    float* __restrict__ z_src_ws, float* __restrict__ z_dst_ws,
    float* __restrict__ mu_out, float* __restrict__ lam_out)
{
    __shared__ int sh[256];
    const int b = blockIdx.x;
    const int t = threadIdx.x;

    if (b < SCAN_BLOCKS) {
        const int i = b * 256 + t;
        const int v = (i < N_NODES) ? counts[i] : 0;
        sh[t] = v;
        __syncthreads();
#pragma unroll
        for (int off = 1; off < 256; off <<= 1) {
            int x = (t >= off) ? sh[t - off] : 0;
            __syncthreads();
            sh[t] += x;
            __syncthreads();
        }
        if (i < N_NODES) local[i] = sh[t] - v;
        if (t == 255) bsums[b] = sh[255];
        return;
    }

    // ---- k1b part ----
    const int g = (b - SCAN_BLOCKS) * 256 + t;       // (row, head) flat
    if (g >= N_NODES * NH) return;
    const int row = g >> 2;
    const int h   = g & 3;

    const unsigned short* fr = ft_bf + (size_t)row * HD + h * 32;
    const float* ms = mu_src + h * 32;
    const float* md = mu_dst + h * 32;
    const float* ls = lam_src + h * 32;

    float pm = 0.0f, pd = 0.0f, pl = 0.0f;
#pragma unroll
    for (int v = 0; v < 4; ++v) {
        const us8 u = *(const us8*)(fr + v * 8);
#pragma unroll
        for (int j = 0; j < 8; ++j) {
            const float f = bf2f(u[j]);
            const int   i = v * 8 + j;
            pm = fmaf(f, ms[i], pm);
            pd = fmaf(f, md[i], pd);
            pl = fmaf(f, ls[i], pl);
        }
    }
    const float sdev = expf(0.5f * pl);
    z_src_ws[g] = eps_src[g] * sdev + pm;
    z_dst_ws[g] = eps_dst[g] * sdev + pd;
    mu_out[g]   = pm + pd;
    lam_out[g]  = 2.0f * pl;     // lam_d == lam_s in reference
}

// ---------------------------------------------------------------------------
__global__ __launch_bounds__(256) void k_scan_bsums(
    const int* __restrict__ bsums, int* __restrict__ bscan)
{
    __shared__ int sh[256];
    const int t = threadIdx.x;
    const int v = (t < SCAN_BLOCKS) ? bsums[t] : 0;
    sh[t] = v;
    __syncthreads();
#pragma unroll
    for (int off = 1; off < 256; off <<= 1) {
        int x = (t >= off) ? sh[t - off] : 0;
        __syncthreads();
        sh[t] += x;
        __syncthreads();
    }
    if (t < SCAN_BLOCKS) bscan[t] = sh[t] - v;
}

__global__ __launch_bounds__(256) void k_scan_add(
    const int* __restrict__ local, const int* __restrict__ bscan,
    int* __restrict__ offsets)
{
    const int i = blockIdx.x * 256 + threadIdx.x;
    if (i >= N_NODES) return;
    offsets[i] = local[i] + bscan[blockIdx.x];
}

// ---------------------------------------------------------------------------
// Scatter edges into dst-sorted order. Atomic-free: j = offsets[dst]+rank.
// 16B padded record, nontemporal store.
// ---------------------------------------------------------------------------
__global__ __launch_bounds__(256) void k_scatter(
    const int* __restrict__ src, const int* __restrict__ dst,
    const float* __restrict__ ppmi, const int* __restrict__ rank,
    const int* __restrict__ offsets, v4i* __restrict__ rec_sorted)
{
    const int e = blockIdx.x * 256 + threadIdx.x;
    if (e >= N_EDGES) return;
    const int d0 = dst[e];
    const int j  = offsets[d0] + rank[e];
    v4i rec;
    rec.x = src[e];
    rec.y = __float_as_int(edge_scale(ppmi[e]));
    rec.z = 0;
    rec.w = 0;
    __builtin_nontemporal_store(rec, rec_sorted + j);
}

// ---------------------------------------------------------------------------
// K3: CSR segmented reduction. Wave split 4-ways by edge: 16 lanes x 16B
// cover a 256B ft row, 4 edges in flight (8 with the 2x unroll). Cross-lane
// shfl_xor(16,32) folds replicas; each replica writes a disjoint f2 slice.
// ---------------------------------------------------------------------------
__device__ __forceinline__ float edge_w1(float zs, float zd, float sc)
{
    float v = zs + zd;
    v = (v >= 0.0f) ? v : NEG_SLOPE * v;
    return __expf(v * sc);
}

__global__ __launch_bounds__(64) void k3_csr(
    const int* __restrict__ offsets, const int* __restrict__ counts,
    const v4i* __restrict__ rec_sorted,
    const float* __restrict__ z_src_ws, const float* __restrict__ z_dst_ws,
    const uint4* __restrict__ ft_u128, float2* __restrict__ rst2)
{
    const int node = blockIdx.x;
    const int lane = threadIdx.x;
    const int es   = lane >> 4;        // edge subset 0..3
    const int li   = lane & 15;        // 16B slot within ft row
    const int h    = li >> 2;          // head of this lane's 8 cols
    const int start = offsets[node];
    const int deg   = counts[node];
    const float zd  = z_dst_ws[node * NH + h];

    float acc[8] = {0, 0, 0, 0, 0, 0, 0, 0};
    float wsum = 0.0f;

#define K3_EDGE(EI)                                                            \
    do {                                                                       \
        const int  ei  = (EI);                                                 \
        const int  idx = start + ((ei < deg) ? ei : 0);                        \
        const v4i  r   = __builtin_nontemporal_load(rec_sorted + idx);         \
        const float zs = z_src_ws[r.x * NH + h];                               \
        const uint4 f  = ft_u128[(size_t)r.x * 16 + li];                       \
        float w = edge_w1(zs, zd, __int_as_float(r.y));                        \
        if (ei >= deg) w = 0.0f;                                               \
        acc[0] = fmaf(bf2f(f.x & 0xffffu), w, acc[0]);                         \
        acc[1] = fmaf(bf2f(f.x >> 16),     w, acc[1]);                         \
        acc[2] = fmaf(bf2f(f.y & 0xffffu), w, acc[2]);                         \
        acc[3] = fmaf(bf2f(f.y >> 16),     w, acc[3]);                         \
        acc[4] = fmaf(bf2f(f.z & 0xffffu), w, acc[4]);                         \
        acc[5] = fmaf(bf2f(f.z >> 16),     w, acc[5]);                         \
        acc[6] = fmaf(bf2f(f.w & 0xffffu), w, acc[6]);                         \
        acc[7] = fmaf(bf2f(f.w >> 16),     w, acc[7]);                         \
        wsum += w;                                                             \
    } while (0)

    int i = 0;
    for (; i + 8 <= deg; i += 8) {       // two independent chains
        K3_EDGE(i + es);
        K3_EDGE(i + 4 + es);
    }
    if (i < deg) K3_EDGE(i + es);        // masked tail (covers deg-i in 1..8)
    if (i + 4 < deg) K3_EDGE(i + 4 + es);

    // fold the 4 edge-subset replicas (lanes differing in bits 4 and 5)
#pragma unroll
    for (int m = 16; m <= 32; m <<= 1) {
        wsum += __shfl_xor(wsum, m, 64);
#pragma unroll
        for (int j = 0; j < 8; ++j) acc[j] += __shfl_xor(acc[j], m, 64);
    }

    const float inv = (wsum > 0.0f) ? 1.0f / wsum : 0.0f;
    // replica es writes cols [li*8 + es*2, +1]  -> full 128-col row coalesced
    rst2[(size_t)node * 64 + li * 4 + es] =
        make_float2(acc[es * 2] * inv, acc[es * 2 + 1] * inv);
}

// ---------------------------------------------------------------------------
extern "C" void kernel_launch(void* const* d_in, const int* in_sizes, int n_in,
                              void* d_out, int out_size, void* d_ws, size_t ws_size,
                              hipStream_t stream)
{
    const float* feat    = (const float*)d_in[0];
    const int*   src     = (const int*)  d_in[1];
    const int*   dst     = (const int*)  d_in[2];
    const float* ppmi    = (const float*)d_in[3];
    const float* eps_src = (const float*)d_in[4];
    const float* eps_dst = (const float*)d_in[5];
    const float* W       = (const float*)d_in[6];
    const float* mu_src  = (const float*)d_in[7];
    const float* mu_dst  = (const float*)d_in[8];
    const float* lam_src = (const float*)d_in[9];
    // d_in[10] = lam_dst: unused by the reference math

    float* out     = (float*)d_out;
    float* rst     = out;                                 // N*HD
    float* mu_out  = out + (size_t)N_NODES * HD;          // N*NH
    float* lam_out = mu_out + (size_t)N_NODES * NH;       // N*NH

    // workspace layout (16B-aligned first)
    char* wsb = (char*)d_ws;
    v4i*            rec_s  = (v4i*)wsb;                                    // E*16B
    unsigned short* ft_bf  = (unsigned short*)(wsb + (size_t)N_EDGES * 16);// N*HD*2
    unsigned short* Wt_bf  = ft_bf + (size_t)N_NODES * HD;                 // 128*256
    float*          zs_ws  = (float*)(Wt_bf + (size_t)HD * IN_DIM);
    float*          zd_ws  = zs_ws + (size_t)N_NODES * NH;
    int*            counts = (int*)(zd_ws + (size_t)N_NODES * NH);
    int*            local  = counts + N_NODES;
    int*            offsets= local + N_NODES;
    int*            bsums  = offsets + N_NODES;
    int*            bscan  = bsums + 256;
    int*            rank   = bscan + 256;                                  // E

    hipMemsetAsync(counts, 0, N_NODES * sizeof(int), stream);

    k_wt_hist<<<HIST_BLOCKS + WT_BLOCKS, 256, 0, stream>>>(
        W, Wt_bf, dst, counts, rank);

    k1_mfma<<<(N_NODES + 127) / 128, 256, 0, stream>>>(feat, Wt_bf, ft_bf);

    k_k1b_scanlocal<<<SCAN_BLOCKS + K1B_BLOCKS, 256, 0, stream>>>(
        counts, local, bsums,
        ft_bf, mu_src, mu_dst, lam_src, eps_src, eps_dst,
        zs_ws, zd_ws, mu_out, lam_out);

    k_scan_bsums<<<1, 256, 0, stream>>>(bsums, bscan);
    k_scan_add<<<SCAN_BLOCKS, 256, 0, stream>>>(local, bscan, offsets);

    k_scatter<<<HIST_BLOCKS, 256, 0, stream>>>(
        src, dst, ppmi, rank, offsets, rec_s);

    k3_csr<<<N_NODES, 64, 0, stream>>>(
        offsets, counts, rec_s, zs_ws, zd_ws,
        (const uint4*)ft_bf, (float2*)rst);
}